// Round 8
// baseline (1875.901 us; speedup 1.0000x reference)
//
#include <hip/hip_runtime.h>
#include <cmath>

#define BATCH 16
#define SEQ 512
#define DMODEL 512
#define NDEPTH 4
#define NHEADS 8
#define DHEAD 64
#define DFF 2048
#define CBD 64
#define CBS 8192
#define MROWS (BATCH * SEQ) // 8192

typedef unsigned short u16;
typedef __attribute__((ext_vector_type(8))) short short8; // 8 bf16 = 4 VGPRs (MFMA A/B frag)
typedef __attribute__((ext_vector_type(4))) float f32x4;  // MFMA C/D frag
typedef __attribute__((ext_vector_type(4))) unsigned short u16x4;

// ---------------------------------------------------------------- bf16 helpers
__device__ __forceinline__ u16 f2bf(float f) {
    unsigned u = __float_as_uint(f);
    u += 0x7fff + ((u >> 16) & 1); // RNE
    return (u16)(u >> 16);
}
__device__ __forceinline__ float bf2f(u16 h) {
    return __uint_as_float(((unsigned)h) << 16);
}

// async global->LDS 16B: LDS dest must be wave-uniform base + lane*16
__device__ __forceinline__ void async16(u16* lds, const u16* g) {
    __builtin_amdgcn_global_load_lds(
        (const __attribute__((address_space(1))) unsigned int*)g,
        (__attribute__((address_space(3))) unsigned int*)lds, 16, 0, 0);
}

// gelu(u) = 0.5u(1+tanh(y)) = u*sigmoid(2y) — exp-form, __expf -> v_exp_f32
__device__ __forceinline__ float gelu_tanh(float u) {
    float t = fmaf(0.07135481627f * u, u * u, 1.5957691216f * u);
    return u / (1.0f + __expf(-t));
}

// ---------------------------------------------------------------- zero output
__global__ void zero_kernel(float* __restrict__ p, int n) {
    int i = blockIdx.x * 256 + threadIdx.x;
    if (i < n) p[i] = 0.0f;
}

// ------------------------------------------------------------- codebook norms
__global__ void cbn_kernel(const float* __restrict__ cb, float* __restrict__ cbn) {
    int c = blockIdx.x * 256 + threadIdx.x;
    if (c >= CBS) return;
    const float* row = cb + (size_t)c * CBD;
    float s = 0.0f;
#pragma unroll
    for (int d = 0; d < CBD; ++d) s += row[d] * row[d];
    cbn[c] = s;
}

// ------------------------- weight transpose + split: W [z][K][N] -> T [z][N][K]
__global__ __launch_bounds__(256) void wtrans_kernel(
    const float* __restrict__ W, u16* __restrict__ Th, u16* __restrict__ Tl,
    int K, int N, long inLS, long outLS) {
    __shared__ float t[32][33];
    const float* Ws = W + (size_t)blockIdx.z * inLS;
    u16* Tho = Th + (size_t)blockIdx.z * outLS;
    u16* Tlo = Tl + (size_t)blockIdx.z * outLS;
    int n0 = blockIdx.x * 32, k0 = blockIdx.y * 32;
    int tx = threadIdx.x & 31, ty = threadIdx.x >> 5;
#pragma unroll
    for (int r = ty; r < 32; r += 8) t[r][tx] = Ws[(size_t)(k0 + r) * N + n0 + tx];
    __syncthreads();
#pragma unroll
    for (int r = ty; r < 32; r += 8) {
        float v = t[tx][r];
        size_t o = (size_t)(n0 + r) * K + k0 + tx;
        u16 hh = f2bf(v);
        Tho[o] = hh;
        Tlo[o] = f2bf(v - bf2f(hh));
    }
}

// ---------------- V transpose: head-major qkv slot [16+h][M][64] -> VT [b][d][s]
__global__ __launch_bounds__(256) void vtrans_kernel(
    const u16* __restrict__ Qh, const u16* __restrict__ Ql,
    u16* __restrict__ VTh, u16* __restrict__ VTl) {
    __shared__ u16 t[64][68];
    int s0 = blockIdx.x * 64;       // seq tile
    int hh = blockIdx.y;            // head
    int b = blockIdx.z & 15, plane = blockIdx.z >> 4;
    const u16* src = (plane ? Ql : Qh) + ((size_t)(16 + hh) * MROWS) * 64;
    u16* dst = (plane ? VTl : VTh);
    int tid = threadIdx.x;
    int rr = tid >> 4, c4 = (tid & 15) * 4;
#pragma unroll
    for (int i = 0; i < 4; ++i) {
        int r = rr + i * 16; // seq within tile
        const u16* p = src + (size_t)(b * SEQ + s0 + r) * 64 + c4;
        *(u16x4*)(&t[r][c4]) = *(const u16x4*)p;
    }
    __syncthreads();
#pragma unroll
    for (int i = 0; i < 4; ++i) {
        int r = rr + i * 16; // d-index within head
        u16x4 v;
        v.x = t[c4 + 0][r]; v.y = t[c4 + 1][r]; v.z = t[c4 + 2][r]; v.w = t[c4 + 3][r];
        *(u16x4*)(dst + (size_t)b * SEQ * DMODEL + (size_t)(hh * 64 + r) * SEQ + s0 + c4) = v;
    }
}

// ------------------------------------------------ elementwise fp32 -> (hi,lo)
__global__ void split_kernel(const float* __restrict__ X, u16* __restrict__ H,
                             u16* __restrict__ L, int n) {
    int i = blockIdx.x * 256 + threadIdx.x;
    if (i < n) {
        float v = X[i];
        u16 hh = f2bf(v);
        H[i] = hh;
        L[i] = f2bf(v - bf2f(hh));
    }
}

// ---------------------------------------- layernorm (+split-K reduce folding)
__global__ __launch_bounds__(256) void ln_kernel(
    const float* __restrict__ X,
    const float* __restrict__ C0, const float* __restrict__ C1,
    const float* __restrict__ bias2, const float* __restrict__ pos2,
    float* __restrict__ Xout,
    float* __restrict__ Y, u16* __restrict__ Yh, u16* __restrict__ Yl,
    const float* __restrict__ g, const float* __restrict__ b) {
    int row  = blockIdx.x * 4 + (threadIdx.x >> 6);
    int lane = threadIdx.x & 63;
    float v[8];
    float s = 0.0f;
#pragma unroll
    for (int j = 0; j < 8; ++j) {
        int d = lane + j * 64;
        size_t o = (size_t)row * DMODEL + d;
        float t = X ? X[o] : 0.0f;
        if (C0)    t += C0[o] + C1[o];
        if (bias2) t += bias2[d];
        if (pos2)  t += pos2[(size_t)(row & (SEQ - 1)) * DMODEL + d];
        v[j] = t;
        if (Xout) Xout[o] = t;
        s += t;
    }
#pragma unroll
    for (int off = 32; off; off >>= 1) s += __shfl_xor(s, off);
    float mu  = s * (1.0f / DMODEL);
    float var = 0.0f;
#pragma unroll
    for (int j = 0; j < 8; ++j) { float d = v[j] - mu; var += d * d; }
#pragma unroll
    for (int off = 32; off; off >>= 1) var += __shfl_xor(var, off);
    float r = rsqrtf(var * (1.0f / DMODEL) + 1e-5f);
#pragma unroll
    for (int j = 0; j < 8; ++j) {
        int d = lane + j * 64;
        float y = (v[j] - mu) * r * g[d] + b[d];
        size_t o = (size_t)row * DMODEL + d;
        if (Y) Y[o] = y;
        if (Yh) {
            u16 hh = f2bf(y);
            Yh[o] = hh;
            Yl[o] = f2bf(y - bf2f(hh));
        }
    }
}

// --------------------------------------------------------- bf16x3 MFMA GEMM
// BK=64, XOR-swizzled LDS (conflict-free frag reads), 96 MFMA per barrier-pair.
// kslice>0: split-K partials -> Cs0/Cs1. qkvscatter: store C head-major.
__global__ __launch_bounds__(256) void gemm3_kernel(
    const u16* __restrict__ Ah, const u16* __restrict__ Al,
    const u16* __restrict__ Bh, const u16* __restrict__ Bl,
    float* __restrict__ Cf, u16* __restrict__ Ch, u16* __restrict__ Cl,
    const float* __restrict__ bias, const float* __restrict__ res,
    const float* __restrict__ pos, int M, int N, int K, int gelu,
    float* __restrict__ Cs0, float* __restrict__ Cs1, int kslice, int qkvscatter) {
    __shared__ __align__(16) u16 AsH[128 * 64];
    __shared__ __align__(16) u16 AsL[128 * 64];
    __shared__ __align__(16) u16 BsH[128 * 64];
    __shared__ __align__(16) u16 BsL[128 * 64];

    int tid  = threadIdx.x;
    int w    = tid >> 6, lane = tid & 63;
    int wr   = w >> 1, wc = w & 1;
    int quad = lane >> 4, l16 = lane & 15;
    int m0   = blockIdx.x * 128;
    int n0   = blockIdx.y * 128;
    int ksA  = (kslice > 0) ? blockIdx.z * kslice : 0;
    int ksB  = (kslice > 0) ? ksA + kslice : K;

    f32x4 acc[4][4];
#pragma unroll
    for (int i = 0; i < 4; ++i)
#pragma unroll
        for (int j = 0; j < 4; ++j) acc[i][j] = (f32x4){0.f, 0.f, 0.f, 0.f};

    int ldsoff[4];
    size_t goff[4];
#pragma unroll
    for (int r = 0; r < 4; ++r) {
        int cidx = tid + 256 * r;
        int row = cidx >> 3;
        int cg = (cidx & 7) ^ (row & 7);
        ldsoff[r] = cidx * 8;
        goff[r] = (size_t)row * K + cg * 8;
    }

    const u16* AbaseH = Ah + (size_t)m0 * K;
    const u16* AbaseL = Al + (size_t)m0 * K;
    const u16* BbaseH = Bh + (size_t)n0 * K;
    const u16* BbaseL = Bl + (size_t)n0 * K;

    for (int ks = ksA; ks < ksB; ks += 64) {
        __syncthreads();
#pragma unroll
        for (int r = 0; r < 4; ++r) {
            size_t g = goff[r] + ks;
            async16(&AsH[ldsoff[r]], AbaseH + g);
            async16(&AsL[ldsoff[r]], AbaseL + g);
            async16(&BsH[ldsoff[r]], BbaseH + g);
            async16(&BsL[ldsoff[r]], BbaseL + g);
        }
        __syncthreads();
#pragma unroll
        for (int s = 0; s < 2; ++s) {
            short8 afh[4], afl[4];
#pragma unroll
            for (int i = 0; i < 4; ++i) {
                int row = wr * 64 + i * 16 + l16;
                int off = row * 64 + (((s << 2) | quad) ^ (row & 7)) * 8;
                afh[i] = *(const short8*)&AsH[off];
                afl[i] = *(const short8*)&AsL[off];
            }
#pragma unroll
            for (int j = 0; j < 4; ++j) {
                int rowb = wc * 64 + j * 16 + l16;
                int offb = rowb * 64 + (((s << 2) | quad) ^ (rowb & 7)) * 8;
                short8 bh = *(const short8*)&BsH[offb];
                short8 bl = *(const short8*)&BsL[offb];
#pragma unroll
                for (int i = 0; i < 4; ++i) {
                    acc[i][j] = __builtin_amdgcn_mfma_f32_16x16x32_bf16(afh[i], bh, acc[i][j], 0, 0, 0);
                    acc[i][j] = __builtin_amdgcn_mfma_f32_16x16x32_bf16(afl[i], bh, acc[i][j], 0, 0, 0);
                    acc[i][j] = __builtin_amdgcn_mfma_f32_16x16x32_bf16(afh[i], bl, acc[i][j], 0, 0, 0);
                }
            }
        }
    }

    float* Cspl = (kslice > 0) ? (blockIdx.z ? Cs1 : Cs0) : nullptr;
    int mbase = m0 + wr * 64;
    int nbase = n0 + wc * 64;
#pragma unroll
    for (int mi = 0; mi < 4; ++mi)
#pragma unroll
        for (int ni = 0; ni < 4; ++ni) {
            f32x4 a = acc[mi][ni];
#pragma unroll
            for (int r = 0; r < 4; ++r) {
                int m = mbase + mi * 16 + quad * 4 + r;
                int n = nbase + ni * 16 + l16;
                float v = a[r];
                size_t o = qkvscatter
                    ? ((size_t)(n >> 6) * M + m) * 64 + (n & 63)
                    : (size_t)m * N + n;
                if (Cspl) { Cspl[o] = v; continue; }
                if (bias) v += bias[n];
                if (pos)  v += pos[(size_t)(m & (SEQ - 1)) * N + n];
                if (res)  v += res[(size_t)m * N + n];
                if (gelu) v = gelu_tanh(v);
                if (Cf) Cf[o] = v;
                if (Ch) {
                    u16 hh = f2bf(v);
                    Ch[o] = hh;
                    Cl[o] = f2bf(v - bf2f(hh));
                }
            }
        }
}

// ------------------------------------------------------------ fp32 GEMM (small)
__global__ __launch_bounds__(256) void gemm_kernel(
    const float* __restrict__ A, const float* __restrict__ Bm,
    float* __restrict__ C, const float* __restrict__ bias,
    int M, int N, int K) {
    __shared__ float As[16][68];
    __shared__ float Bs[16][64];
    int tid = threadIdx.x;
    int tx = tid & 15, ty = tid >> 4;
    int a_m = tid >> 2, a_k = (tid & 3) * 4;
    int b_k = tid >> 4, b_n = (tid & 15) * 4;
    const float* Arow = A + (size_t)(blockIdx.x * 64 + a_m) * K;
    const float* Bcol = Bm + (size_t)blockIdx.y * 64 + b_n;
    float acc[4][4] = {};
    for (int k0 = 0; k0 < K; k0 += 16) {
        float4 av = *(const float4*)(Arow + k0 + a_k);
        float4 bv = *(const float4*)(Bcol + (size_t)(k0 + b_k) * N);
        __syncthreads();
        As[a_k + 0][a_m] = av.x; As[a_k + 1][a_m] = av.y;
        As[a_k + 2][a_m] = av.z; As[a_k + 3][a_m] = av.w;
        *(float4*)(&Bs[b_k][b_n]) = bv;
        __syncthreads();
#pragma unroll
        for (int kk = 0; kk < 16; ++kk) {
            float4 a4 = *(const float4*)(&As[kk][ty * 4]);
            float4 b4 = *(const float4*)(&Bs[kk][tx * 4]);
            float ar[4] = {a4.x, a4.y, a4.z, a4.w};
            float br[4] = {b4.x, b4.y, b4.z, b4.w};
#pragma unroll
            for (int i = 0; i < 4; ++i)
#pragma unroll
                for (int j = 0; j < 4; ++j) acc[i][j] = fmaf(ar[i], br[j], acc[i][j]);
        }
    }
    int m0 = blockIdx.x * 64 + ty * 4;
    int n0 = blockIdx.y * 64 + tx * 4;
#pragma unroll
    for (int i = 0; i < 4; ++i) {
        float vv[4];
#pragma unroll
        for (int j = 0; j < 4; ++j) {
            float t = acc[i][j];
            if (bias) t += bias[n0 + j];
            vv[j] = t;
        }
        *(float4*)(C + (size_t)(m0 + i) * N + n0) = make_float4(vv[0], vv[1], vv[2], vv[3]);
    }
}

// ------------------------------------------- flash attention (STATIC-max softmax)
// ROUND 8: per-wave memory ILP. Rounds 0-7 established: runtime invariant to
// occupancy (22-44%) and per-block work; ~74 cy per load-instr per CU => each
// wave keeps ~1 gather-load in flight (register-starved at VGPR 48) against
// ~600-1000cy L2/L3 latency. Fix: deep register prefetch — 2 K banks + 1 V
// bank software pipeline, 8-12 loads in flight per wave. VGPR is ALLOWED to
// grow (~118, still <=128 -> 4 waves/SIMD); registers ARE outstanding loads.
// Static-max softmax retained (P=exp(s/8), single epilogue row-sum reduce).
__global__ __launch_bounds__(256) void attn_flash_kernel(
    const u16* __restrict__ QKh, const u16* __restrict__ QKl,
    const u16* __restrict__ VTh, const u16* __restrict__ VTl,
    u16* __restrict__ Oh, u16* __restrict__ Ol) {
    int bh = blockIdx.x & 127;
    int qt = blockIdx.x >> 7;   // 0..7
    int bb = bh >> 3, hh = bh & 7;

    __shared__ __align__(16) float Pw[4][16 * 68]; // wave-private P tiles (17408 B)

    int tid = threadIdx.x;
    int w = tid >> 6, lane = tid & 63;
    int quad = lane >> 4, l16 = lane & 15;
    int qtile = qt * 4 + w;     // 0..31
    float* P = Pw[w];

    const u16* qrh = QKh + ((size_t)hh * MROWS + bb * SEQ + qtile * 16 + l16) * 64 + quad * 8;
    const u16* qrl = QKl + ((size_t)hh * MROWS + bb * SEQ + qtile * 16 + l16) * 64 + quad * 8;
    short8 Qh0 = *(const short8*)qrh;
    short8 Qh1 = *(const short8*)(qrh + 32);
    short8 Ql0 = *(const short8*)qrl;
    short8 Ql1 = *(const short8*)(qrl + 32);

    float lsum[4] = {0.f, 0.f, 0.f, 0.f};   // per-lane partial row sums
    f32x4 acc[4];
#pragma unroll
    for (int dt = 0; dt < 4; ++dt) acc[dt] = (f32x4){0.f, 0.f, 0.f, 0.f};

    const u16* KbH = QKh + ((size_t)(8 + hh) * MROWS + bb * SEQ) * 64;
    const u16* KbL = QKl + ((size_t)(8 + hh) * MROWS + bb * SEQ) * 64;
    const u16* VbH = VTh + (size_t)bb * SEQ * DMODEL + (size_t)(hh * 64) * SEQ;
    const u16* VbL = VTl + (size_t)bb * SEQ * DMODEL + (size_t)(hh * 64) * SEQ;

    // K banks (16 VGPR each) and V bank (32 VGPR), all individually named.
    short8 Kah0, Kah1, Kal0, Kal1;
    short8 Kbh0, Kbh1, Kbl0, Kbl1;
    short8 V0h, V0l, V1h, V1l, V2h, V2l, V3h, V3l;
    short8 ph, pl;

#define LOADK(bk, row_) {                                          \
    const u16* kh_ = KbH + (size_t)(row_) * 64 + quad * 8;         \
    const u16* kl_ = KbL + (size_t)(row_) * 64 + quad * 8;         \
    bk##h0 = *(const short8*)kh_;  bk##h1 = *(const short8*)(kh_ + 32); \
    bk##l0 = *(const short8*)kl_;  bk##l1 = *(const short8*)(kl_ + 32); }

#define QKC(bk, sidx_) {                                                        \
    f32x4 a_ = (f32x4){0.f, 0.f, 0.f, 0.f};                                     \
    a_ = __builtin_amdgcn_mfma_f32_16x16x32_bf16(Qh0, bk##h0, a_, 0, 0, 0);     \
    a_ = __builtin_amdgcn_mfma_f32_16x16x32_bf16(Qh1, bk##h1, a_, 0, 0, 0);     \
    a_ = __builtin_amdgcn_mfma_f32_16x16x32_bf16(Ql0, bk##h0, a_, 0, 0, 0);     \
    a_ = __builtin_amdgcn_mfma_f32_16x16x32_bf16(Ql1, bk##h1, a_, 0, 0, 0);     \
    a_ = __builtin_amdgcn_mfma_f32_16x16x32_bf16(Qh0, bk##l0, a_, 0, 0, 0);     \
    a_ = __builtin_amdgcn_mfma_f32_16x16x32_bf16(Qh1, bk##l1, a_, 0, 0, 0);     \
    _Pragma("unroll")                                                           \
    for (int r = 0; r < 4; ++r) {                                               \
        float p_ = __expf(a_[r] * 0.125f);                                      \
        lsum[r] += p_;                                                          \
        P[(quad * 4 + r) * 68 + (sidx_) * 16 + l16] = p_;                       \
    } }

#define LOADV(ks_) {                                                            \
    size_t vcol_ = (size_t)kb + (ks_) * 32 + quad * 8;                          \
    V0h = *(const short8*)(VbH + (size_t)(0 * 16 + l16) * SEQ + vcol_);         \
    V0l = *(const short8*)(VbL + (size_t)(0 * 16 + l16) * SEQ + vcol_);         \
    V1h = *(const short8*)(VbH + (size_t)(1 * 16 + l16) * SEQ + vcol_);         \
    V1l = *(const short8*)(VbL + (size_t)(1 * 16 + l16) * SEQ + vcol_);         \
    V2h = *(const short8*)(VbH + (size_t)(2 * 16 + l16) * SEQ + vcol_);         \
    V2l = *(const short8*)(VbL + (size_t)(2 * 16 + l16) * SEQ + vcol_);         \
    V3h = *(const short8*)(VbH + (size_t)(3 * 16 + l16) * SEQ + vcol_);         \
    V3l = *(const short8*)(VbL + (size_t)(3 * 16 + l16) * SEQ + vcol_); }

#define PACKP(ks_) {                                                            \
    const float* src_ = &P[l16 * 68 + (ks_) * 32 + quad * 8];                   \
    f32x4 a0_ = *(const f32x4*)src_;                                            \
    f32x4 a1_ = *(const f32x4*)(src_ + 4);                                      \
    float vv_[8] = {a0_[0], a0_[1], a0_[2], a0_[3], a1_[0], a1_[1], a1_[2], a1_[3]}; \
    _Pragma("unroll")                                                           \
    for (int j = 0; j < 8; ++j) {                                               \
        u16 hv_ = f2bf(vv_[j]);                                                 \
        ph[j] = (short)hv_;                                                     \
        pl[j] = (short)f2bf(vv_[j] - bf2f(hv_));                                \
    } }

#define PVC() {                                                                 \
    acc[0] = __builtin_amdgcn_mfma_f32_16x16x32_bf16(ph, V0h, acc[0], 0, 0, 0); \
    acc[1] = __builtin_amdgcn_mfma_f32_16x16x32_bf16(ph, V1h, acc[1], 0, 0, 0); \
    acc[2] = __builtin_amdgcn_mfma_f32_16x16x32_bf16(ph, V2h, acc[2], 0, 0, 0); \
    acc[3] = __builtin_amdgcn_mfma_f32_16x16x32_bf16(ph, V3h, acc[3], 0, 0, 0); \
    acc[0] = __builtin_amdgcn_mfma_f32_16x16x32_bf16(pl, V0h, acc[0], 0, 0, 0); \
    acc[1] = __builtin_amdgcn_mfma_f32_16x16x32_bf16(pl, V1h, acc[1], 0, 0, 0); \
    acc[2] = __builtin_amdgcn_mfma_f32_16x16x32_bf16(pl, V2h, acc[2], 0, 0, 0); \
    acc[3] = __builtin_amdgcn_mfma_f32_16x16x32_bf16(pl, V3h, acc[3], 0, 0, 0); \
    acc[0] = __builtin_amdgcn_mfma_f32_16x16x32_bf16(ph, V0l, acc[0], 0, 0, 0); \
    acc[1] = __builtin_amdgcn_mfma_f32_16x16x32_bf16(ph, V1l, acc[1], 0, 0, 0); \
    acc[2] = __builtin_amdgcn_mfma_f32_16x16x32_bf16(ph, V2l, acc[2], 0, 0, 0); \
    acc[3] = __builtin_amdgcn_mfma_f32_16x16x32_bf16(ph, V3l, acc[3], 0, 0, 0); }

    // prologue: prefetch kt=0 s=0,1
    LOADK(Ka, 0 + l16);
    LOADK(Kb, 16 + l16);

    for (int kt = 0; kt < 8; ++kt) {
        int kb  = kt * 64;
        int kbn = ((kt + 1) & 7) * 64;   // kt=7 wraps: harmless prefetch, unused
        QKC(Ka, 0);
        LOADK(Ka, kb + 32 + l16);        // s=2 -> bank A
        QKC(Kb, 1);
        LOADK(Kb, kb + 48 + l16);        // s=3 -> bank B
        LOADV(0);                        // V ks=0 in flight under s=2,3 compute
        QKC(Ka, 2);
        QKC(Kb, 3);
        LOADK(Ka, kbn + 0 + l16);        // next kt s=0 (banks free)
        LOADK(Kb, kbn + 16 + l16);       // next kt s=1
        PACKP(0);
        PVC();
        LOADV(1);                        // V ks=1 (V bank free after PV ks=0)
        PACKP(1);
        PVC();
    }

#undef LOADK
#undef QKC
#undef LOADV
#undef PACKP
#undef PVC

    // ---- epilogue: single row-sum reduce (within each quad's 16 lanes) ----
#pragma unroll
    for (int r = 0; r < 4; ++r) {
#pragma unroll
        for (int off = 8; off; off >>= 1) lsum[r] += __shfl_xor(lsum[r], off);
    }
#pragma unroll
    for (int r = 0; r < 4; ++r) {
        float inv = 1.0f / lsum[r];
        size_t rowoff = (size_t)(bb * SEQ + qtile * 16 + quad * 4 + r) * DMODEL + hh * 64;
#pragma unroll
        for (int dt = 0; dt < 4; ++dt) {
            float v = acc[dt][r] * inv;
            u16 hv = f2bf(v);
            Oh[rowoff + dt * 16 + l16] = hv;
            Ol[rowoff + dt * 16 + l16] = f2bf(v - bf2f(hv));
        }
    }
}

// ----------------------------------------------------------------- MFMA VQ
// ROUND 8: 4 waves/block (R6 shape), 4 register banks (A-D), prefetch
// distance 3 compute-phases (~650cy) so code loads land before use. ~10
// loads in flight per wave vs ~1. Ascending scan + strict-less compare ->
// identical argmin. Wrap-masked prefetch on the last iterations loads valid
// memory that is never computed.
__global__ __launch_bounds__(256) void vq3_kernel(
    const float* __restrict__ Z, const u16* __restrict__ Zh, const u16* __restrict__ Zl,
    const u16* __restrict__ CBh, const u16* __restrict__ CBl,
    const float* __restrict__ CB, const float* __restrict__ CBN,
    float* __restrict__ out) {
    __shared__ float sbest[4][16];
    __shared__ int sidx[4][16];
    __shared__ int ibest[16];
    __shared__ float psum[4][64];
    __shared__ float cl4[4];

    int tid = threadIdx.x;
    int w = tid >> 6, lane = tid & 63;
    int quad = lane >> 4, l16 = lane & 15;
    int row0 = blockIdx.x * 16;

    const u16* zph = Zh + (size_t)(row0 + l16) * CBD + quad * 8;
    const u16* zpl = Zl + (size_t)(row0 + l16) * CBD + quad * 8;
    short8 Z0h = *(const short8*)zph;
    short8 Z1h = *(const short8*)(zph + 32);
    short8 Z0l = *(const short8*)zpl;
    short8 Z1l = *(const short8*)(zpl + 32);

    float best[4] = {3.4e38f, 3.4e38f, 3.4e38f, 3.4e38f};
    int bidx[4] = {0, 0, 0, 0};

    short8 A0h, A1h, A0l, A1l;  float An;
    short8 B0h, B1h, B0l, B1l;  float Bn;
    short8 C0h, C1h, C0l, C1l;  float Cn;
    short8 D0h, D1h, D0l, D1l;  float Dn;

#define LOADB(bk, cc) {                                            \
    int c_ = (cc);                                                 \
    const u16* ph_ = CBh + (size_t)c_ * CBD + quad * 8;            \
    const u16* pl_ = CBl + (size_t)c_ * CBD + quad * 8;            \
    bk##0h = *(const short8*)ph_;  bk##1h = *(const short8*)(ph_ + 32); \
    bk##0l = *(const short8*)pl_;  bk##1l = *(const short8*)(pl_ + 32); \
    bk##n  = CBN[c_]; }

#define COMPB(bk, cc) {                                                          \
    f32x4 a_ = (f32x4){0.f, 0.f, 0.f, 0.f};                                      \
    int c_ = (cc);                                                               \
    a_ = __builtin_amdgcn_mfma_f32_16x16x32_bf16(Z0h, bk##0h, a_, 0, 0, 0);      \
    a_ = __builtin_amdgcn_mfma_f32_16x16x32_bf16(Z1h, bk##1h, a_, 0, 0, 0);      \
    a_ = __builtin_amdgcn_mfma_f32_16x16x32_bf16(Z0l, bk##0h, a_, 0, 0, 0);      \
    a_ = __builtin_amdgcn_mfma_f32_16x16x32_bf16(Z1l, bk##1h, a_, 0, 0, 0);      \
    a_ = __builtin_amdgcn_mfma_f32_16x16x32_bf16(Z0h, bk##0l, a_, 0, 0, 0);      \
    a_ = __builtin_amdgcn_mfma_f32_16x16x32_bf16(Z1h, bk##1l, a_, 0, 0, 0);      \
    _Pragma("unroll")                                                            \
    for (int r = 0; r < 4; ++r) {                                                \
        float s_ = bk##n - 2.0f * a_[r];                                         \
        if (s_ < best[r]) { best[r] = s_; bidx[r] = c_; }                        \
    } }

    const int NW = CBS / 4;          // 2048 codes per wave
    int cbase = w * NW;
    LOADB(A, cbase + l16);
    LOADB(B, cbase + 16 + l16);
    LOADB(C, cbase + 32 + l16);
    LOADB(D, cbase + 48 + l16);
    for (int t = 0; t < NW; t += 64) {
        COMPB(A, cbase + t + l16);       LOADB(A, cbase + ((t + 64)  & (NW - 1)) + l16);
        COMPB(B, cbase + t + 16 + l16);  LOADB(B, cbase + ((t + 80)  & (NW - 1)) + l16);
        COMPB(C, cbase + t + 32 + l16);  LOADB(C, cbase + ((t + 96)  & (NW - 1)) + l16);
        COMPB(D, cbase + t + 48 + l16);  LOADB(D, cbase + ((t + 112) & (NW - 1)) + l16);
    }

#undef LOADB
#undef COMPB

#pragma unroll
    for (int off = 8; off; off >>= 1) {
#pragma unroll
        for (int r = 0; r < 4; ++r) {
            float ov = __shfl_xor(best[r], off);
            int oi = __shfl_xor(bidx[r], off);
            if (ov < best[r] || (ov == best[r] && oi < bidx[r])) { best[r] = ov; bidx[r] = oi; }
        }
    }
    if (l16 == 0) {
#pragma unroll
        for (int r = 0; r < 4; ++r) {
            sbest[w][quad * 4 + r] = best[r];
            sidx[w][quad * 4 + r] = bidx[r];
        }
    }
    __syncthreads();
    if (tid < 16) {
        float bv = sbest[0][tid];
        int bi = sidx[0][tid];
#pragma unroll
        for (int ww = 1; ww < 4; ++ww) {
            float ov = sbest[ww][tid];
            int oi = sidx[ww][tid];
            if (ov < bv || (ov == bv && oi < bi)) { bv = ov; bi = oi; }
        }
        ibest[tid] = bi;
    }
    __syncthreads();

    int d2 = lane;
    float qacc = 0.0f, closs = 0.0f;
#pragma unroll
    for (int j = 0; j < 4; ++j) {
        int r2 = w * 4 + j;
        int bi = ibest[r2];
        float q = CB[(size_t)bi * CBD + d2];
        float z = Z[(size_t)(row0 + r2) * CBD + d2];
        qacc += q;
        float df = q - z;
        closs += df * df;
    }
    psum[w][d2] = qacc;
#pragma unroll
    for (int off = 32; off; off >>= 1) closs += __shfl_xor(closs, off);
    if (d2 == 0) cl4[w] = closs;
    __syncthreads();
    if (tid < 64) {
        float t = psum[0][tid] + psum[1][tid] + psum[2][tid] + psum[3][tid];
        int b = row0 >> 9;
        atomicAdd(out + b * 64 + tid, t);
    }
    if (tid == 0)
        atomicAdd(out + 1024, (cl4[0] + cl4[1] + cl4[2] + cl4[3]) * (1.0f / (float)(MROWS * CBD)));
}

// -------------------------------------------------------------------- launch
extern "C" void kernel_launch(void* const* d_in, const int* in_sizes, int n_in,
                              void* d_out, int out_size, void* d_ws, size_t ws_size,
                              hipStream_t stream) {
    const float* x    = (const float*)d_in[0];
    const float* w_in = (const float*)d_in[1];
    const float* b_in = (const float*)d_in[2];
    const float* pos  = (const float*)d_in[3];
    const float* ln1g = (const float*)d_in[4];
    const float* ln1b = (const float*)d_in[5];
    const float* wq   = (const float*)d_in[6];
    const float* wk   = (const float*)d_in[7];
    const float* wv   = (const float*)d_in[8];
    const float* wo   = (const float*)d_in[9];
    const float* ln2g = (const float*)d_in[10];
    const float* ln2b = (const float*)d_in[11];
    const float* ffw1 = (const float*)d_in[12];
    const float* ffb1 = (const float*)d_in[13];
    const float* ffw2 = (const float*)d_in[14];
    const float* ffb2 = (const float*)d_in[15];
    const float* lnfg = (const float*)d_in[16];
    const float* lnfb = (const float*)d_in[17];
    const float* wout = (const float*)d_in[18];
    const float* bout = (const float*)d_in[19];
    const float* cb   = (const float*)d_in[20];
    float* out = (float*)d_out;

    const size_t MD  = (size_t)MROWS * DMODEL;   // 4,194,304
    const size_t MQ  = (size_t)MROWS * 1536;     // 12,582,912
    const size_t MF  = (size_t)MROWS * DFF;      // 16,777,216

    float* ws   = (float*)d_ws;
    float* h    = ws;
    float* t0   = h + MD;
    float* big  = t0 + MD;                   // MF floats (aliased region)
    float* zb   = big + MF;
    float* cbn  = zb + (size_t)MROWS * CBD;
    u16* cbh    = (u16*)(cbn + CBS);
    u16* cbl    = cbh + (size_t)CBS * CBD;
    u16* t0h    = (u16*)(cbh + 2 * (size_t)CBS * CBD);
    u16* t0l    = t0h + MD;
    u16* wb     = t0l + MD;

    // big aliases
    u16* qkvh = (u16*)big;
    u16* qkvl = qkvh + MQ;
    u16* obh  = qkvl + MQ;
    u16* obl  = obh + MD;
    u16* xh   = obh;
    u16* xl   = obl;
    u16* fmh  = (u16*)big;
    u16* fml  = fmh + MF;
    u16* zbh  = (u16*)big;        // VQ phase: big region is dead
    u16* zbl  = zbh + (size_t)MROWS * CBD;

    const size_t S_WIN  = (size_t)DMODEL * DMODEL;
    const size_t S_QKV  = (size_t)1536 * DMODEL * NDEPTH;
    const size_t S_WO   = S_WIN * NDEPTH;
    const size_t S_FF1  = (size_t)DFF * DMODEL * NDEPTH;
    const size_t S_FF2  = S_FF1;
    u16* winT_h = wb;
    u16* winT_l = winT_h + S_WIN;
    u16* qkvT_h = winT_l + S_WIN;
    u16* qkvT_l = qkvT_h + S_QKV;
    u16* woT_h  = qkvT_l + S_QKV;
    u16* woT_l  = woT_h + S_WO;
    u16* ff1T_h = woT_l + S_WO;
    u16* ff1T_l = ff1T_h + S_FF1;
    u16* ff2T_h = ff1T_l + S_FF1;
    u16* ff2T_l = ff2T_h + S_FF2;
    u16* VTh = ff2T_l + S_FF2;
    u16* VTl = VTh + (size_t)BATCH * SEQ * DMODEL;
    // split-K partial buffers (fp32, M x 512 each)
    float* spK0 = (float*)(VTl + (size_t)BATCH * SEQ * DMODEL);
    float* spK1 = spK0 + MD;

    dim3 blk(256);

    zero_kernel<<<dim3((out_size + 255) / 256), blk, 0, stream>>>(out, out_size);
    cbn_kernel<<<dim3(CBS / 256), blk, 0, stream>>>(cb, cbn);
    split_kernel<<<dim3((int)(CBS * CBD / 256)), blk, 0, stream>>>(cb, cbh, cbl, CBS * CBD);

    wtrans_kernel<<<dim3(16, 16, 1), blk, 0, stream>>>(w_in, winT_h, winT_l, DMODEL, DMODEL, 0, 0);
    wtrans_kernel<<<dim3(16, 16, NDEPTH), blk, 0, stream>>>(
        wq, qkvT_h, qkvT_l, DMODEL, DMODEL, (long)DMODEL * DMODEL, (long)1536 * DMODEL);
    wtrans_kernel<<<dim3(16, 16, NDEPTH), blk, 0, stream>>>(
        wk, qkvT_h + (size_t)512 * DMODEL, qkvT_l + (size_t)512 * DMODEL,
        DMODEL, DMODEL, (long)DMODEL * DMODEL, (long)1536 * DMODEL);
    wtrans_kernel<<<dim3(16, 16, NDEPTH), blk, 0, stream>>>(
        wv, qkvT_h + (size_t)1024 * DMODEL, qkvT_l + (size_t)1024 * DMODEL,
        DMODEL, DMODEL, (long)DMODEL * DMODEL, (long)1536 * DMODEL);
    wtrans_kernel<<<dim3(16, 16, NDEPTH), blk, 0, stream>>>(
        wo, woT_h, woT_l, DMODEL, DMODEL, (long)DMODEL * DMODEL, (long)DMODEL * DMODEL);
    wtrans_kernel<<<dim3(DFF / 32, 16, NDEPTH), blk, 0, stream>>>(
        ffw1, ff1T_h, ff1T_l, DMODEL, DFF, (long)DMODEL * DFF, (long)DFF * DMODEL);
    wtrans_kernel<<<dim3(16, DFF / 32, NDEPTH), blk, 0, stream>>>(
        ffw2, ff2T_h, ff2T_l, DFF, DMODEL, (long)DFF * DMODEL, (long)DMODEL * DFF);

    split_kernel<<<dim3((int)(MD / 256)), blk, 0, stream>>>(x, xh, xl, (int)MD);

    // input projection: split-K=2 -> spK0/spK1 (reduced+pos+bias inside ln1 of layer 0)
    gemm3_kernel<<<dim3(MROWS / 128, DMODEL / 128, 2), blk, 0, stream>>>(
        xh, xl, winT_h, winT_l, nullptr, nullptr, nullptr, nullptr, nullptr, nullptr,
        MROWS, DMODEL, DMODEL, 0, spK0, spK1, 256, 0);

    for (int l = 0; l < NDEPTH; ++l) {
        // ln1 folds: l==0 -> input proj (+b_in+pos); l>0 -> previous ff2 (+ffb2[l-1])
        ln_kernel<<<dim3(MROWS / 4), blk, 0, stream>>>(
            (l == 0) ? nullptr : h, spK0, spK1,
            (l == 0) ? b_in : (ffb2 + (size_t)(l - 1) * DMODEL),
            (l == 0) ? pos : nullptr, h,
            nullptr, t0h, t0l, ln1g + l * DMODEL, ln1b + l * DMODEL);
        // fused QKV -> head-major split planes (slot = part*8+head, each [M][64])
        gemm3_kernel<<<dim3(MROWS / 128, 1536 / 128, 1), blk, 0, stream>>>(
            t0h, t0l, qkvT_h + (size_t)l * 1536 * DMODEL, qkvT_l + (size_t)l * 1536 * DMODEL,
            nullptr, qkvh, qkvl, nullptr, nullptr, nullptr, MROWS, 1536, DMODEL, 0,
            nullptr, nullptr, 0, 1);
        vtrans_kernel<<<dim3(8, 8, 32), blk, 0, stream>>>(qkvh, qkvl, VTh, VTl);
        attn_flash_kernel<<<dim3(1024), blk, 0, stream>>>(
            qkvh, qkvl, VTh, VTl, obh, obl);
        // wo: split-K=2 (reduced + residual inside ln2)
        gemm3_kernel<<<dim3(MROWS / 128, DMODEL / 128, 2), blk, 0, stream>>>(
            obh, obl, woT_h + (size_t)l * S_WIN, woT_l + (size_t)l * S_WIN,
            nullptr, nullptr, nullptr, nullptr, nullptr, nullptr,
            MROWS, DMODEL, DMODEL, 0, spK0, spK1, 256, 0);
        ln_kernel<<<dim3(MROWS / 4), blk, 0, stream>>>(
            h, spK0, spK1, nullptr, nullptr, h,
            nullptr, t0h, t0l, ln2g + l * DMODEL, ln2b + l * DMODEL);
        gemm3_kernel<<<dim3(MROWS / 128, DFF / 128, 1), blk, 0, stream>>>(
            t0h, t0l, ff1T_h + (size_t)l * DFF * DMODEL, ff1T_l + (size_t)l * DFF * DMODEL,
            nullptr, fmh, fml, ffb1 + l * DFF, nullptr, nullptr, MROWS, DFF, DMODEL, 1,
            nullptr, nullptr, 0, 0);
        // ff2: split-K=2 over K=2048 (reduced + ffb2 + residual in next ln1/lnf)
        gemm3_kernel<<<dim3(MROWS / 128, DMODEL / 128, 2), blk, 0, stream>>>(
            fmh, fml, ff2T_h + (size_t)l * DFF * DMODEL, ff2T_l + (size_t)l * DFF * DMODEL,
            nullptr, nullptr, nullptr, nullptr, nullptr, nullptr,
            MROWS, DMODEL, DFF, 0, spK0, spK1, 1024, 0);
    }

    // final ln folds last ff2 (+ffb2[3]); writes fp32 t0 for the out-projection
    ln_kernel<<<dim3(MROWS / 4), blk, 0, stream>>>(
        h, spK0, spK1, ffb2 + (size_t)3 * DMODEL, nullptr, nullptr,
        t0, nullptr, nullptr, lnfg, lnfb);
    gemm_kernel<<<dim3(MROWS / 64, 1), blk, 0, stream>>>(t0, wout, zb, bout, MROWS, CBD, DMODEL);
    split_kernel<<<dim3((int)((size_t)MROWS * CBD / 256)), blk, 0, stream>>>(
        zb, zbh, zbl, MROWS * CBD);
    vq3_kernel<<<dim3(MROWS / 16), blk, 0, stream>>>(zb, zbh, zbl, cbh, cbl, cb, cbn, out);
}

// Round 9
// 1811.160 us; speedup vs baseline: 1.0357x; 1.0357x over previous
//
#include <hip/hip_runtime.h>
#include <cmath>

#define BATCH 16
#define SEQ 512
#define DMODEL 512
#define NDEPTH 4
#define NHEADS 8
#define DHEAD 64
#define DFF 2048
#define CBD 64
#define CBS 8192
#define MROWS (BATCH * SEQ) // 8192

typedef unsigned short u16;
typedef __attribute__((ext_vector_type(8))) short short8; // 8 bf16 = 4 VGPRs (MFMA A/B frag)
typedef __attribute__((ext_vector_type(4))) float f32x4;  // MFMA C/D frag
typedef __attribute__((ext_vector_type(4))) unsigned short u16x4;

// ---------------------------------------------------------------- bf16 helpers
__device__ __forceinline__ u16 f2bf(float f) {
    unsigned u = __float_as_uint(f);
    u += 0x7fff + ((u >> 16) & 1); // RNE
    return (u16)(u >> 16);
}
__device__ __forceinline__ float bf2f(u16 h) {
    return __uint_as_float(((unsigned)h) << 16);
}

// async global->LDS 16B: LDS dest must be wave-uniform base + lane*16
__device__ __forceinline__ void async16(u16* lds, const u16* g) {
    __builtin_amdgcn_global_load_lds(
        (const __attribute__((address_space(1))) unsigned int*)g,
        (__attribute__((address_space(3))) unsigned int*)lds, 16, 0, 0);
}

// gelu(u) = 0.5u(1+tanh(y)) = u*sigmoid(2y) — exp-form, __expf -> v_exp_f32
__device__ __forceinline__ float gelu_tanh(float u) {
    float t = fmaf(0.07135481627f * u, u * u, 1.5957691216f * u);
    return u / (1.0f + __expf(-t));
}

// ---------------------------------------------------------------- zero output
__global__ void zero_kernel(float* __restrict__ p, int n) {
    int i = blockIdx.x * 256 + threadIdx.x;
    if (i < n) p[i] = 0.0f;
}

// ------------------------------------------------------------- codebook norms
__global__ void cbn_kernel(const float* __restrict__ cb, float* __restrict__ cbn) {
    int c = blockIdx.x * 256 + threadIdx.x;
    if (c >= CBS) return;
    const float* row = cb + (size_t)c * CBD;
    float s = 0.0f;
#pragma unroll
    for (int d = 0; d < CBD; ++d) s += row[d] * row[d];
    cbn[c] = s;
}

// ------------------------- weight transpose + split: W [z][K][N] -> T [z][N][K]
__global__ __launch_bounds__(256) void wtrans_kernel(
    const float* __restrict__ W, u16* __restrict__ Th, u16* __restrict__ Tl,
    int K, int N, long inLS, long outLS) {
    __shared__ float t[32][33];
    const float* Ws = W + (size_t)blockIdx.z * inLS;
    u16* Tho = Th + (size_t)blockIdx.z * outLS;
    u16* Tlo = Tl + (size_t)blockIdx.z * outLS;
    int n0 = blockIdx.x * 32, k0 = blockIdx.y * 32;
    int tx = threadIdx.x & 31, ty = threadIdx.x >> 5;
#pragma unroll
    for (int r = ty; r < 32; r += 8) t[r][tx] = Ws[(size_t)(k0 + r) * N + n0 + tx];
    __syncthreads();
#pragma unroll
    for (int r = ty; r < 32; r += 8) {
        float v = t[tx][r];
        size_t o = (size_t)(n0 + r) * K + k0 + tx;
        u16 hh = f2bf(v);
        Tho[o] = hh;
        Tlo[o] = f2bf(v - bf2f(hh));
    }
}

// ---------------- V transpose: head-major qkv slot [16+h][M][64] -> VT [b][d][s]
__global__ __launch_bounds__(256) void vtrans_kernel(
    const u16* __restrict__ Qh, const u16* __restrict__ Ql,
    u16* __restrict__ VTh, u16* __restrict__ VTl) {
    __shared__ u16 t[64][68];
    int s0 = blockIdx.x * 64;       // seq tile
    int hh = blockIdx.y;            // head
    int b = blockIdx.z & 15, plane = blockIdx.z >> 4;
    const u16* src = (plane ? Ql : Qh) + ((size_t)(16 + hh) * MROWS) * 64;
    u16* dst = (plane ? VTl : VTh);
    int tid = threadIdx.x;
    int rr = tid >> 4, c4 = (tid & 15) * 4;
#pragma unroll
    for (int i = 0; i < 4; ++i) {
        int r = rr + i * 16; // seq within tile
        const u16* p = src + (size_t)(b * SEQ + s0 + r) * 64 + c4;
        *(u16x4*)(&t[r][c4]) = *(const u16x4*)p;
    }
    __syncthreads();
#pragma unroll
    for (int i = 0; i < 4; ++i) {
        int r = rr + i * 16; // d-index within head
        u16x4 v;
        v.x = t[c4 + 0][r]; v.y = t[c4 + 1][r]; v.z = t[c4 + 2][r]; v.w = t[c4 + 3][r];
        *(u16x4*)(dst + (size_t)b * SEQ * DMODEL + (size_t)(hh * 64 + r) * SEQ + s0 + c4) = v;
    }
}

// ------------------------------------------------ elementwise fp32 -> (hi,lo)
__global__ void split_kernel(const float* __restrict__ X, u16* __restrict__ H,
                             u16* __restrict__ L, int n) {
    int i = blockIdx.x * 256 + threadIdx.x;
    if (i < n) {
        float v = X[i];
        u16 hh = f2bf(v);
        H[i] = hh;
        L[i] = f2bf(v - bf2f(hh));
    }
}

// ---------------------------------------- layernorm (+split-K reduce folding)
__global__ __launch_bounds__(256) void ln_kernel(
    const float* __restrict__ X,
    const float* __restrict__ C0, const float* __restrict__ C1,
    const float* __restrict__ bias2, const float* __restrict__ pos2,
    float* __restrict__ Xout,
    float* __restrict__ Y, u16* __restrict__ Yh, u16* __restrict__ Yl,
    const float* __restrict__ g, const float* __restrict__ b) {
    int row  = blockIdx.x * 4 + (threadIdx.x >> 6);
    int lane = threadIdx.x & 63;
    float v[8];
    float s = 0.0f;
#pragma unroll
    for (int j = 0; j < 8; ++j) {
        int d = lane + j * 64;
        size_t o = (size_t)row * DMODEL + d;
        float t = X ? X[o] : 0.0f;
        if (C0)    t += C0[o] + C1[o];
        if (bias2) t += bias2[d];
        if (pos2)  t += pos2[(size_t)(row & (SEQ - 1)) * DMODEL + d];
        v[j] = t;
        if (Xout) Xout[o] = t;
        s += t;
    }
#pragma unroll
    for (int off = 32; off; off >>= 1) s += __shfl_xor(s, off);
    float mu  = s * (1.0f / DMODEL);
    float var = 0.0f;
#pragma unroll
    for (int j = 0; j < 8; ++j) { float d = v[j] - mu; var += d * d; }
#pragma unroll
    for (int off = 32; off; off >>= 1) var += __shfl_xor(var, off);
    float r = rsqrtf(var * (1.0f / DMODEL) + 1e-5f);
#pragma unroll
    for (int j = 0; j < 8; ++j) {
        int d = lane + j * 64;
        float y = (v[j] - mu) * r * g[d] + b[d];
        size_t o = (size_t)row * DMODEL + d;
        if (Y) Y[o] = y;
        if (Yh) {
            u16 hh = f2bf(y);
            Yh[o] = hh;
            Yl[o] = f2bf(y - bf2f(hh));
        }
    }
}

// --------------------------------------------------------- bf16x3 MFMA GEMM
// BK=64, XOR-swizzled LDS (conflict-free frag reads), 96 MFMA per barrier-pair.
// kslice>0: split-K partials -> Cs0/Cs1. qkvscatter: store C head-major.
__global__ __launch_bounds__(256) void gemm3_kernel(
    const u16* __restrict__ Ah, const u16* __restrict__ Al,
    const u16* __restrict__ Bh, const u16* __restrict__ Bl,
    float* __restrict__ Cf, u16* __restrict__ Ch, u16* __restrict__ Cl,
    const float* __restrict__ bias, const float* __restrict__ res,
    const float* __restrict__ pos, int M, int N, int K, int gelu,
    float* __restrict__ Cs0, float* __restrict__ Cs1, int kslice, int qkvscatter) {
    __shared__ __align__(16) u16 AsH[128 * 64];
    __shared__ __align__(16) u16 AsL[128 * 64];
    __shared__ __align__(16) u16 BsH[128 * 64];
    __shared__ __align__(16) u16 BsL[128 * 64];

    int tid  = threadIdx.x;
    int w    = tid >> 6, lane = tid & 63;
    int wr   = w >> 1, wc = w & 1;
    int quad = lane >> 4, l16 = lane & 15;
    int m0   = blockIdx.x * 128;
    int n0   = blockIdx.y * 128;
    int ksA  = (kslice > 0) ? blockIdx.z * kslice : 0;
    int ksB  = (kslice > 0) ? ksA + kslice : K;

    f32x4 acc[4][4];
#pragma unroll
    for (int i = 0; i < 4; ++i)
#pragma unroll
        for (int j = 0; j < 4; ++j) acc[i][j] = (f32x4){0.f, 0.f, 0.f, 0.f};

    int ldsoff[4];
    size_t goff[4];
#pragma unroll
    for (int r = 0; r < 4; ++r) {
        int cidx = tid + 256 * r;
        int row = cidx >> 3;
        int cg = (cidx & 7) ^ (row & 7);
        ldsoff[r] = cidx * 8;
        goff[r] = (size_t)row * K + cg * 8;
    }

    const u16* AbaseH = Ah + (size_t)m0 * K;
    const u16* AbaseL = Al + (size_t)m0 * K;
    const u16* BbaseH = Bh + (size_t)n0 * K;
    const u16* BbaseL = Bl + (size_t)n0 * K;

    for (int ks = ksA; ks < ksB; ks += 64) {
        __syncthreads();
#pragma unroll
        for (int r = 0; r < 4; ++r) {
            size_t g = goff[r] + ks;
            async16(&AsH[ldsoff[r]], AbaseH + g);
            async16(&AsL[ldsoff[r]], AbaseL + g);
            async16(&BsH[ldsoff[r]], BbaseH + g);
            async16(&BsL[ldsoff[r]], BbaseL + g);
        }
        __syncthreads();
#pragma unroll
        for (int s = 0; s < 2; ++s) {
            short8 afh[4], afl[4];
#pragma unroll
            for (int i = 0; i < 4; ++i) {
                int row = wr * 64 + i * 16 + l16;
                int off = row * 64 + (((s << 2) | quad) ^ (row & 7)) * 8;
                afh[i] = *(const short8*)&AsH[off];
                afl[i] = *(const short8*)&AsL[off];
            }
#pragma unroll
            for (int j = 0; j < 4; ++j) {
                int rowb = wc * 64 + j * 16 + l16;
                int offb = rowb * 64 + (((s << 2) | quad) ^ (rowb & 7)) * 8;
                short8 bh = *(const short8*)&BsH[offb];
                short8 bl = *(const short8*)&BsL[offb];
#pragma unroll
                for (int i = 0; i < 4; ++i) {
                    acc[i][j] = __builtin_amdgcn_mfma_f32_16x16x32_bf16(afh[i], bh, acc[i][j], 0, 0, 0);
                    acc[i][j] = __builtin_amdgcn_mfma_f32_16x16x32_bf16(afl[i], bh, acc[i][j], 0, 0, 0);
                    acc[i][j] = __builtin_amdgcn_mfma_f32_16x16x32_bf16(afh[i], bl, acc[i][j], 0, 0, 0);
                }
            }
        }
    }

    float* Cspl = (kslice > 0) ? (blockIdx.z ? Cs1 : Cs0) : nullptr;
    int mbase = m0 + wr * 64;
    int nbase = n0 + wc * 64;
#pragma unroll
    for (int mi = 0; mi < 4; ++mi)
#pragma unroll
        for (int ni = 0; ni < 4; ++ni) {
            f32x4 a = acc[mi][ni];
#pragma unroll
            for (int r = 0; r < 4; ++r) {
                int m = mbase + mi * 16 + quad * 4 + r;
                int n = nbase + ni * 16 + l16;
                float v = a[r];
                size_t o = qkvscatter
                    ? ((size_t)(n >> 6) * M + m) * 64 + (n & 63)
                    : (size_t)m * N + n;
                if (Cspl) { Cspl[o] = v; continue; }
                if (bias) v += bias[n];
                if (pos)  v += pos[(size_t)(m & (SEQ - 1)) * N + n];
                if (res)  v += res[(size_t)m * N + n];
                if (gelu) v = gelu_tanh(v);
                if (Cf) Cf[o] = v;
                if (Ch) {
                    u16 hh = f2bf(v);
                    Ch[o] = hh;
                    Cl[o] = f2bf(v - bf2f(hh));
                }
            }
        }
}

// ------------------------------------------------------------ fp32 GEMM (small)
__global__ __launch_bounds__(256) void gemm_kernel(
    const float* __restrict__ A, const float* __restrict__ Bm,
    float* __restrict__ C, const float* __restrict__ bias,
    int M, int N, int K) {
    __shared__ float As[16][68];
    __shared__ float Bs[16][64];
    int tid = threadIdx.x;
    int tx = tid & 15, ty = tid >> 4;
    int a_m = tid >> 2, a_k = (tid & 3) * 4;
    int b_k = tid >> 4, b_n = (tid & 15) * 4;
    const float* Arow = A + (size_t)(blockIdx.x * 64 + a_m) * K;
    const float* Bcol = Bm + (size_t)blockIdx.y * 64 + b_n;
    float acc[4][4] = {};
    for (int k0 = 0; k0 < K; k0 += 16) {
        float4 av = *(const float4*)(Arow + k0 + a_k);
        float4 bv = *(const float4*)(Bcol + (size_t)(k0 + b_k) * N);
        __syncthreads();
        As[a_k + 0][a_m] = av.x; As[a_k + 1][a_m] = av.y;
        As[a_k + 2][a_m] = av.z; As[a_k + 3][a_m] = av.w;
        *(float4*)(&Bs[b_k][b_n]) = bv;
        __syncthreads();
#pragma unroll
        for (int kk = 0; kk < 16; ++kk) {
            float4 a4 = *(const float4*)(&As[kk][ty * 4]);
            float4 b4 = *(const float4*)(&Bs[kk][tx * 4]);
            float ar[4] = {a4.x, a4.y, a4.z, a4.w};
            float br[4] = {b4.x, b4.y, b4.z, b4.w};
#pragma unroll
            for (int i = 0; i < 4; ++i)
#pragma unroll
                for (int j = 0; j < 4; ++j) acc[i][j] = fmaf(ar[i], br[j], acc[i][j]);
        }
    }
    int m0 = blockIdx.x * 64 + ty * 4;
    int n0 = blockIdx.y * 64 + tx * 4;
#pragma unroll
    for (int i = 0; i < 4; ++i) {
        float vv[4];
#pragma unroll
        for (int j = 0; j < 4; ++j) {
            float t = acc[i][j];
            if (bias) t += bias[n0 + j];
            vv[j] = t;
        }
        *(float4*)(C + (size_t)(m0 + i) * N + n0) = make_float4(vv[0], vv[1], vv[2], vv[3]);
    }
}

// ------------------------------------------- flash attention (STATIC-max softmax)
// PROVEN R6/R7 version (125.6us, VGPR 48, occ 44%) — restored verbatim after
// round 8's deep-prefetch variant regressed (VGPR 72 -> occupancy halved AND
// FETCH +61% from broken L2 locality; 184us). Serial-path bound; static-max
// softmax (P = exp(s/8), scores bounded, single epilogue row-sum reduce).
__global__ __launch_bounds__(256) void attn_flash_kernel(
    const u16* __restrict__ QKh, const u16* __restrict__ QKl,
    const u16* __restrict__ VTh, const u16* __restrict__ VTl,
    u16* __restrict__ Oh, u16* __restrict__ Ol) {
    int bh = blockIdx.x & 127;
    int qt = blockIdx.x >> 7;   // 0..7
    int bb = bh >> 3, hh = bh & 7;

    __shared__ __align__(16) float Pw[4][16 * 68]; // wave-private P tiles (17408 B)

    int tid = threadIdx.x;
    int w = tid >> 6, lane = tid & 63;
    int quad = lane >> 4, l16 = lane & 15;
    int qtile = qt * 4 + w;     // 0..31
    float* P = Pw[w];

    const u16* qrh = QKh + ((size_t)hh * MROWS + bb * SEQ + qtile * 16 + l16) * 64 + quad * 8;
    const u16* qrl = QKl + ((size_t)hh * MROWS + bb * SEQ + qtile * 16 + l16) * 64 + quad * 8;
    short8 Qh0 = *(const short8*)qrh;
    short8 Qh1 = *(const short8*)(qrh + 32);
    short8 Ql0 = *(const short8*)qrl;
    short8 Ql1 = *(const short8*)(qrl + 32);

    float lsum[4] = {0.f, 0.f, 0.f, 0.f};   // per-lane partial row sums
    f32x4 acc[4];
#pragma unroll
    for (int dt = 0; dt < 4; ++dt) acc[dt] = (f32x4){0.f, 0.f, 0.f, 0.f};

    const u16* KbH = QKh + ((size_t)(8 + hh) * MROWS + bb * SEQ) * 64;
    const u16* KbL = QKl + ((size_t)(8 + hh) * MROWS + bb * SEQ) * 64;
    const u16* VbH = VTh + (size_t)bb * SEQ * DMODEL + (size_t)(hh * 64) * SEQ;
    const u16* VbL = VTl + (size_t)bb * SEQ * DMODEL + (size_t)(hh * 64) * SEQ;

    for (int kt = 0; kt < 8; ++kt) {
        int kb = kt * 64;
        // ---- QK^T -> P = exp(score/8), accumulate per-lane row sums ----
#pragma unroll
        for (int s = 0; s < 4; ++s) {
            const u16* kh = KbH + (size_t)(kb + s * 16 + l16) * 64 + quad * 8;
            const u16* kl = KbL + (size_t)(kb + s * 16 + l16) * 64 + quad * 8;
            f32x4 a = (f32x4){0.f, 0.f, 0.f, 0.f};
            {   // hi-plane K (transient 8 regs)
                short8 Kh0 = *(const short8*)kh;
                short8 Kh1 = *(const short8*)(kh + 32);
                a = __builtin_amdgcn_mfma_f32_16x16x32_bf16(Qh0, Kh0, a, 0, 0, 0);
                a = __builtin_amdgcn_mfma_f32_16x16x32_bf16(Qh1, Kh1, a, 0, 0, 0);
                a = __builtin_amdgcn_mfma_f32_16x16x32_bf16(Ql0, Kh0, a, 0, 0, 0);
                a = __builtin_amdgcn_mfma_f32_16x16x32_bf16(Ql1, Kh1, a, 0, 0, 0);
            }
            {   // lo-plane K
                short8 Kl0 = *(const short8*)kl;
                short8 Kl1 = *(const short8*)(kl + 32);
                a = __builtin_amdgcn_mfma_f32_16x16x32_bf16(Qh0, Kl0, a, 0, 0, 0);
                a = __builtin_amdgcn_mfma_f32_16x16x32_bf16(Qh1, Kl1, a, 0, 0, 0);
            }
#pragma unroll
            for (int r = 0; r < 4; ++r) {
                float p = __expf(a[r] * 0.125f);
                lsum[r] += p;
                P[(quad * 4 + r) * 68 + s * 16 + l16] = p;
            }
        }
        // ---- PV: ks-outer, ph/pl 8 regs live ----
#pragma unroll
        for (int ks = 0; ks < 2; ++ks) {
            short8 ph, pl;
            {
                const float* src = &P[l16 * 68 + ks * 32 + quad * 8];
                f32x4 a0 = *(const f32x4*)src;
                f32x4 a1 = *(const f32x4*)(src + 4);
                float v[8] = {a0[0], a0[1], a0[2], a0[3], a1[0], a1[1], a1[2], a1[3]};
#pragma unroll
                for (int j = 0; j < 8; ++j) {
                    u16 hv = f2bf(v[j]);
                    ph[j] = (short)hv;
                    pl[j] = (short)f2bf(v[j] - bf2f(hv));
                }
            }
#pragma unroll
            for (int dt = 0; dt < 4; ++dt) {
                const u16* vh = VbH + (size_t)(dt * 16 + l16) * SEQ + kb + ks * 32 + quad * 8;
                const u16* vl = VbL + (size_t)(dt * 16 + l16) * SEQ + kb + ks * 32 + quad * 8;
                short8 Vh = *(const short8*)vh;
                short8 Vl = *(const short8*)vl;
                acc[dt] = __builtin_amdgcn_mfma_f32_16x16x32_bf16(ph, Vh, acc[dt], 0, 0, 0);
                acc[dt] = __builtin_amdgcn_mfma_f32_16x16x32_bf16(pl, Vh, acc[dt], 0, 0, 0);
                acc[dt] = __builtin_amdgcn_mfma_f32_16x16x32_bf16(ph, Vl, acc[dt], 0, 0, 0);
            }
        }
    }

    // ---- epilogue: single row-sum reduce (within each quad's 16 lanes) ----
#pragma unroll
    for (int r = 0; r < 4; ++r) {
#pragma unroll
        for (int off = 8; off; off >>= 1) lsum[r] += __shfl_xor(lsum[r], off);
    }
#pragma unroll
    for (int r = 0; r < 4; ++r) {
        float inv = 1.0f / lsum[r];
        size_t rowoff = (size_t)(bb * SEQ + qtile * 16 + quad * 4 + r) * DMODEL + hh * 64;
#pragma unroll
        for (int dt = 0; dt < 4; ++dt) {
            float v = acc[dt][r] * inv;
            u16 hv = f2bf(v);
            Oh[rowoff + dt * 16 + l16] = hv;
            Ol[rowoff + dt * 16 + l16] = f2bf(v - bf2f(hv));
        }
    }
}

// ----------------------------------------------------------------- MFMA VQ
// KEPT from round 8 (the win of that round): 4 waves/block, 4 register banks
// (A-D), prefetch distance 3 compute-phases — ~10 loads in flight per wave.
// Evidence it improved: R8's top-5 was all attn@183 (vq3 dropped out, was the
// 126us top dispatch before), and the run-total arithmetic implies vq3 got
// ~120us faster. Ascending scan + strict-less compare -> identical argmin.
__global__ __launch_bounds__(256) void vq3_kernel(
    const float* __restrict__ Z, const u16* __restrict__ Zh, const u16* __restrict__ Zl,
    const u16* __restrict__ CBh, const u16* __restrict__ CBl,
    const float* __restrict__ CB, const float* __restrict__ CBN,
    float* __restrict__ out) {
    __shared__ float sbest[4][16];
    __shared__ int sidx[4][16];
    __shared__ int ibest[16];
    __shared__ float psum[4][64];
    __shared__ float cl4[4];

    int tid = threadIdx.x;
    int w = tid >> 6, lane = tid & 63;
    int quad = lane >> 4, l16 = lane & 15;
    int row0 = blockIdx.x * 16;

    const u16* zph = Zh + (size_t)(row0 + l16) * CBD + quad * 8;
    const u16* zpl = Zl + (size_t)(row0 + l16) * CBD + quad * 8;
    short8 Z0h = *(const short8*)zph;
    short8 Z1h = *(const short8*)(zph + 32);
    short8 Z0l = *(const short8*)zpl;
    short8 Z1l = *(const short8*)(zpl + 32);

    float best[4] = {3.4e38f, 3.4e38f, 3.4e38f, 3.4e38f};
    int bidx[4] = {0, 0, 0, 0};

    short8 A0h, A1h, A0l, A1l;  float An;
    short8 B0h, B1h, B0l, B1l;  float Bn;
    short8 C0h, C1h, C0l, C1l;  float Cn;
    short8 D0h, D1h, D0l, D1l;  float Dn;

#define LOADB(bk, cc) {                                            \
    int c_ = (cc);                                                 \
    const u16* ph_ = CBh + (size_t)c_ * CBD + quad * 8;            \
    const u16* pl_ = CBl + (size_t)c_ * CBD + quad * 8;            \
    bk##0h = *(const short8*)ph_;  bk##1h = *(const short8*)(ph_ + 32); \
    bk##0l = *(const short8*)pl_;  bk##1l = *(const short8*)(pl_ + 32); \
    bk##n  = CBN[c_]; }

#define COMPB(bk, cc) {                                                          \
    f32x4 a_ = (f32x4){0.f, 0.f, 0.f, 0.f};                                      \
    int c_ = (cc);                                                               \
    a_ = __builtin_amdgcn_mfma_f32_16x16x32_bf16(Z0h, bk##0h, a_, 0, 0, 0);      \
    a_ = __builtin_amdgcn_mfma_f32_16x16x32_bf16(Z1h, bk##1h, a_, 0, 0, 0);      \
    a_ = __builtin_amdgcn_mfma_f32_16x16x32_bf16(Z0l, bk##0h, a_, 0, 0, 0);      \
    a_ = __builtin_amdgcn_mfma_f32_16x16x32_bf16(Z1l, bk##1h, a_, 0, 0, 0);      \
    a_ = __builtin_amdgcn_mfma_f32_16x16x32_bf16(Z0h, bk##0l, a_, 0, 0, 0);      \
    a_ = __builtin_amdgcn_mfma_f32_16x16x32_bf16(Z1h, bk##1l, a_, 0, 0, 0);      \
    _Pragma("unroll")                                                            \
    for (int r = 0; r < 4; ++r) {                                                \
        float s_ = bk##n - 2.0f * a_[r];                                         \
        if (s_ < best[r]) { best[r] = s_; bidx[r] = c_; }                        \
    } }

    const int NW = CBS / 4;          // 2048 codes per wave
    int cbase = w * NW;
    LOADB(A, cbase + l16);
    LOADB(B, cbase + 16 + l16);
    LOADB(C, cbase + 32 + l16);
    LOADB(D, cbase + 48 + l16);
    for (int t = 0; t < NW; t += 64) {
        COMPB(A, cbase + t + l16);       LOADB(A, cbase + ((t + 64)  & (NW - 1)) + l16);
        COMPB(B, cbase + t + 16 + l16);  LOADB(B, cbase + ((t + 80)  & (NW - 1)) + l16);
        COMPB(C, cbase + t + 32 + l16);  LOADB(C, cbase + ((t + 96)  & (NW - 1)) + l16);
        COMPB(D, cbase + t + 48 + l16);  LOADB(D, cbase + ((t + 112) & (NW - 1)) + l16);
    }

#undef LOADB
#undef COMPB

#pragma unroll
    for (int off = 8; off; off >>= 1) {
#pragma unroll
        for (int r = 0; r < 4; ++r) {
            float ov = __shfl_xor(best[r], off);
            int oi = __shfl_xor(bidx[r], off);
            if (ov < best[r] || (ov == best[r] && oi < bidx[r])) { best[r] = ov; bidx[r] = oi; }
        }
    }
    if (l16 == 0) {
#pragma unroll
        for (int r = 0; r < 4; ++r) {
            sbest[w][quad * 4 + r] = best[r];
            sidx[w][quad * 4 + r] = bidx[r];
        }
    }
    __syncthreads();
    if (tid < 16) {
        float bv = sbest[0][tid];
        int bi = sidx[0][tid];
#pragma unroll
        for (int ww = 1; ww < 4; ++ww) {
            float ov = sbest[ww][tid];
            int oi = sidx[ww][tid];
            if (ov < bv || (ov == bv && oi < bi)) { bv = ov; bi = oi; }
        }
        ibest[tid] = bi;
    }
    __syncthreads();

    int d2 = lane;
    float qacc = 0.0f, closs = 0.0f;
#pragma unroll
    for (int j = 0; j < 4; ++j) {
        int r2 = w * 4 + j;
        int bi = ibest[r2];
        float q = CB[(size_t)bi * CBD + d2];
        float z = Z[(size_t)(row0 + r2) * CBD + d2];
        qacc += q;
        float df = q - z;
        closs += df * df;
    }
    psum[w][d2] = qacc;
#pragma unroll
    for (int off = 32; off; off >>= 1) closs += __shfl_xor(closs, off);
    if (d2 == 0) cl4[w] = closs;
    __syncthreads();
    if (tid < 64) {
        float t = psum[0][tid] + psum[1][tid] + psum[2][tid] + psum[3][tid];
        int b = row0 >> 9;
        atomicAdd(out + b * 64 + tid, t);
    }
    if (tid == 0)
        atomicAdd(out + 1024, (cl4[0] + cl4[1] + cl4[2] + cl4[3]) * (1.0f / (float)(MROWS * CBD)));
}

// -------------------------------------------------------------------- launch
extern "C" void kernel_launch(void* const* d_in, const int* in_sizes, int n_in,
                              void* d_out, int out_size, void* d_ws, size_t ws_size,
                              hipStream_t stream) {
    const float* x    = (const float*)d_in[0];
    const float* w_in = (const float*)d_in[1];
    const float* b_in = (const float*)d_in[2];
    const float* pos  = (const float*)d_in[3];
    const float* ln1g = (const float*)d_in[4];
    const float* ln1b = (const float*)d_in[5];
    const float* wq   = (const float*)d_in[6];
    const float* wk   = (const float*)d_in[7];
    const float* wv   = (const float*)d_in[8];
    const float* wo   = (const float*)d_in[9];
    const float* ln2g = (const float*)d_in[10];
    const float* ln2b = (const float*)d_in[11];
    const float* ffw1 = (const float*)d_in[12];
    const float* ffb1 = (const float*)d_in[13];
    const float* ffw2 = (const float*)d_in[14];
    const float* ffb2 = (const float*)d_in[15];
    const float* lnfg = (const float*)d_in[16];
    const float* lnfb = (const float*)d_in[17];
    const float* wout = (const float*)d_in[18];
    const float* bout = (const float*)d_in[19];
    const float* cb   = (const float*)d_in[20];
    float* out = (float*)d_out;

    const size_t MD  = (size_t)MROWS * DMODEL;   // 4,194,304
    const size_t MQ  = (size_t)MROWS * 1536;     // 12,582,912
    const size_t MF  = (size_t)MROWS * DFF;      // 16,777,216

    float* ws   = (float*)d_ws;
    float* h    = ws;
    float* t0   = h + MD;
    float* big  = t0 + MD;                   // MF floats (aliased region)
    float* zb   = big + MF;
    float* cbn  = zb + (size_t)MROWS * CBD;
    u16* cbh    = (u16*)(cbn + CBS);
    u16* cbl    = cbh + (size_t)CBS * CBD;
    u16* t0h    = (u16*)(cbh + 2 * (size_t)CBS * CBD);
    u16* t0l    = t0h + MD;
    u16* wb     = t0l + MD;

    // big aliases
    u16* qkvh = (u16*)big;
    u16* qkvl = qkvh + MQ;
    u16* obh  = qkvl + MQ;
    u16* obl  = obh + MD;
    u16* xh   = obh;
    u16* xl   = obl;
    u16* fmh  = (u16*)big;
    u16* fml  = fmh + MF;
    u16* zbh  = (u16*)big;        // VQ phase: big region is dead
    u16* zbl  = zbh + (size_t)MROWS * CBD;

    const size_t S_WIN  = (size_t)DMODEL * DMODEL;
    const size_t S_QKV  = (size_t)1536 * DMODEL * NDEPTH;
    const size_t S_WO   = S_WIN * NDEPTH;
    const size_t S_FF1  = (size_t)DFF * DMODEL * NDEPTH;
    const size_t S_FF2  = S_FF1;
    u16* winT_h = wb;
    u16* winT_l = winT_h + S_WIN;
    u16* qkvT_h = winT_l + S_WIN;
    u16* qkvT_l = qkvT_h + S_QKV;
    u16* woT_h  = qkvT_l + S_QKV;
    u16* woT_l  = woT_h + S_WO;
    u16* ff1T_h = woT_l + S_WO;
    u16* ff1T_l = ff1T_h + S_FF1;
    u16* ff2T_h = ff1T_l + S_FF1;
    u16* ff2T_l = ff2T_h + S_FF2;
    u16* VTh = ff2T_l + S_FF2;
    u16* VTl = VTh + (size_t)BATCH * SEQ * DMODEL;
    // split-K partial buffers (fp32, M x 512 each)
    float* spK0 = (float*)(VTl + (size_t)BATCH * SEQ * DMODEL);
    float* spK1 = spK0 + MD;

    dim3 blk(256);

    zero_kernel<<<dim3((out_size + 255) / 256), blk, 0, stream>>>(out, out_size);
    cbn_kernel<<<dim3(CBS / 256), blk, 0, stream>>>(cb, cbn);
    split_kernel<<<dim3((int)(CBS * CBD / 256)), blk, 0, stream>>>(cb, cbh, cbl, CBS * CBD);

    wtrans_kernel<<<dim3(16, 16, 1), blk, 0, stream>>>(w_in, winT_h, winT_l, DMODEL, DMODEL, 0, 0);
    wtrans_kernel<<<dim3(16, 16, NDEPTH), blk, 0, stream>>>(
        wq, qkvT_h, qkvT_l, DMODEL, DMODEL, (long)DMODEL * DMODEL, (long)1536 * DMODEL);
    wtrans_kernel<<<dim3(16, 16, NDEPTH), blk, 0, stream>>>(
        wk, qkvT_h + (size_t)512 * DMODEL, qkvT_l + (size_t)512 * DMODEL,
        DMODEL, DMODEL, (long)DMODEL * DMODEL, (long)1536 * DMODEL);
    wtrans_kernel<<<dim3(16, 16, NDEPTH), blk, 0, stream>>>(
        wv, qkvT_h + (size_t)1024 * DMODEL, qkvT_l + (size_t)1024 * DMODEL,
        DMODEL, DMODEL, (long)DMODEL * DMODEL, (long)1536 * DMODEL);
    wtrans_kernel<<<dim3(16, 16, NDEPTH), blk, 0, stream>>>(
        wo, woT_h, woT_l, DMODEL, DMODEL, (long)DMODEL * DMODEL, (long)DMODEL * DMODEL);
    wtrans_kernel<<<dim3(DFF / 32, 16, NDEPTH), blk, 0, stream>>>(
        ffw1, ff1T_h, ff1T_l, DMODEL, DFF, (long)DMODEL * DFF, (long)DFF * DMODEL);
    wtrans_kernel<<<dim3(16, DFF / 32, NDEPTH), blk, 0, stream>>>(
        ffw2, ff2T_h, ff2T_l, DFF, DMODEL, (long)DFF * DMODEL, (long)DMODEL * DFF);

    split_kernel<<<dim3((int)(MD / 256)), blk, 0, stream>>>(x, xh, xl, (int)MD);

    // input projection: split-K=2 -> spK0/spK1 (reduced+pos+bias inside ln1 of layer 0)
    gemm3_kernel<<<dim3(MROWS / 128, DMODEL / 128, 2), blk, 0, stream>>>(
        xh, xl, winT_h, winT_l, nullptr, nullptr, nullptr, nullptr, nullptr, nullptr,
        MROWS, DMODEL, DMODEL, 0, spK0, spK1, 256, 0);

    for (int l = 0; l < NDEPTH; ++l) {
        // ln1 folds: l==0 -> input proj (+b_in+pos); l>0 -> previous ff2 (+ffb2[l-1])
        ln_kernel<<<dim3(MROWS / 4), blk, 0, stream>>>(
            (l == 0) ? nullptr : h, spK0, spK1,
            (l == 0) ? b_in : (ffb2 + (size_t)(l - 1) * DMODEL),
            (l == 0) ? pos : nullptr, h,
            nullptr, t0h, t0l, ln1g + l * DMODEL, ln1b + l * DMODEL);
        // fused QKV -> head-major split planes (slot = part*8+head, each [M][64])
        gemm3_kernel<<<dim3(MROWS / 128, 1536 / 128, 1), blk, 0, stream>>>(
            t0h, t0l, qkvT_h + (size_t)l * 1536 * DMODEL, qkvT_l + (size_t)l * 1536 * DMODEL,
            nullptr, qkvh, qkvl, nullptr, nullptr, nullptr, MROWS, 1536, DMODEL, 0,
            nullptr, nullptr, 0, 1);
        vtrans_kernel<<<dim3(8, 8, 32), blk, 0, stream>>>(qkvh, qkvl, VTh, VTl);
        attn_flash_kernel<<<dim3(1024), blk, 0, stream>>>(
            qkvh, qkvl, VTh, VTl, obh, obl);
        // wo: split-K=2 (reduced + residual inside ln2)
        gemm3_kernel<<<dim3(MROWS / 128, DMODEL / 128, 2), blk, 0, stream>>>(
            obh, obl, woT_h + (size_t)l * S_WIN, woT_l + (size_t)l * S_WIN,
            nullptr, nullptr, nullptr, nullptr, nullptr, nullptr,
            MROWS, DMODEL, DMODEL, 0, spK0, spK1, 256, 0);
        ln_kernel<<<dim3(MROWS / 4), blk, 0, stream>>>(
            h, spK0, spK1, nullptr, nullptr, h,
            nullptr, t0h, t0l, ln2g + l * DMODEL, ln2b + l * DMODEL);
        gemm3_kernel<<<dim3(MROWS / 128, DFF / 128, 1), blk, 0, stream>>>(
            t0h, t0l, ff1T_h + (size_t)l * DFF * DMODEL, ff1T_l + (size_t)l * DFF * DMODEL,
            nullptr, fmh, fml, ffb1 + l * DFF, nullptr, nullptr, MROWS, DFF, DMODEL, 1,
            nullptr, nullptr, 0, 0);
        // ff2: split-K=2 over K=2048 (reduced + ffb2 + residual in next ln1/lnf)
        gemm3_kernel<<<dim3(MROWS / 128, DMODEL / 128, 2), blk, 0, stream>>>(
            fmh, fml, ff2T_h + (size_t)l * DFF * DMODEL, ff2T_l + (size_t)l * DFF * DMODEL,
            nullptr, nullptr, nullptr, nullptr, nullptr, nullptr,
            MROWS, DMODEL, DFF, 0, spK0, spK1, 1024, 0);
    }

    // final ln folds last ff2 (+ffb2[3]); writes fp32 t0 for the out-projection
    ln_kernel<<<dim3(MROWS / 4), blk, 0, stream>>>(
        h, spK0, spK1, ffb2 + (size_t)3 * DMODEL, nullptr, nullptr,
        t0, nullptr, nullptr, lnfg, lnfb);
    gemm_kernel<<<dim3(MROWS / 64, 1), blk, 0, stream>>>(t0, wout, zb, bout, MROWS, CBD, DMODEL);
    split_kernel<<<dim3((int)((size_t)MROWS * CBD / 256)), blk, 0, stream>>>(
        zb, zbh, zbl, MROWS * CBD);
    vq3_kernel<<<dim3(MROWS / 16), blk, 0, stream>>>(zb, zbh, zbl, cbh, cbl, cb, cbn, out);
}

// Round 10
// 1513.870 us; speedup vs baseline: 1.2391x; 1.1964x over previous
//
#include <hip/hip_runtime.h>
#include <cmath>

#define BATCH 16
#define SEQ 512
#define DMODEL 512
#define NDEPTH 4
#define NHEADS 8
#define DHEAD 64
#define DFF 2048
#define CBD 64
#define CBS 8192
#define MROWS (BATCH * SEQ) // 8192

typedef unsigned short u16;
typedef __attribute__((ext_vector_type(8))) short short8; // 8 bf16 = 4 VGPRs (MFMA A/B frag)
typedef __attribute__((ext_vector_type(4))) float f32x4;  // MFMA C/D frag
typedef __attribute__((ext_vector_type(4))) unsigned short u16x4;

// ---------------------------------------------------------------- bf16 helpers
__device__ __forceinline__ u16 f2bf(float f) {
    unsigned u = __float_as_uint(f);
    u += 0x7fff + ((u >> 16) & 1); // RNE
    return (u16)(u >> 16);
}
__device__ __forceinline__ float bf2f(u16 h) {
    return __uint_as_float(((unsigned)h) << 16);
}

// async global->LDS 16B: LDS dest must be wave-uniform base + lane*16
__device__ __forceinline__ void async16(u16* lds, const u16* g) {
    __builtin_amdgcn_global_load_lds(
        (const __attribute__((address_space(1))) unsigned int*)g,
        (__attribute__((address_space(3))) unsigned int*)lds, 16, 0, 0);
}

// gelu(u) = 0.5u(1+tanh(y)) = u*sigmoid(2y) — exp-form, __expf -> v_exp_f32
__device__ __forceinline__ float gelu_tanh(float u) {
    float t = fmaf(0.07135481627f * u, u * u, 1.5957691216f * u);
    return u / (1.0f + __expf(-t));
}

// ---------------------------------------------------------------- zero output
__global__ void zero_kernel(float* __restrict__ p, int n) {
    int i = blockIdx.x * 256 + threadIdx.x;
    if (i < n) p[i] = 0.0f;
}

// ------------------------------------------------------------- codebook norms
__global__ void cbn_kernel(const float* __restrict__ cb, float* __restrict__ cbn) {
    int c = blockIdx.x * 256 + threadIdx.x;
    if (c >= CBS) return;
    const float* row = cb + (size_t)c * CBD;
    float s = 0.0f;
#pragma unroll
    for (int d = 0; d < CBD; ++d) s += row[d] * row[d];
    cbn[c] = s;
}

// ------------------------- weight transpose + split: W [z][K][N] -> T [z][N][K]
__global__ __launch_bounds__(256) void wtrans_kernel(
    const float* __restrict__ W, u16* __restrict__ Th, u16* __restrict__ Tl,
    int K, int N, long inLS, long outLS) {
    __shared__ float t[32][33];
    const float* Ws = W + (size_t)blockIdx.z * inLS;
    u16* Tho = Th + (size_t)blockIdx.z * outLS;
    u16* Tlo = Tl + (size_t)blockIdx.z * outLS;
    int n0 = blockIdx.x * 32, k0 = blockIdx.y * 32;
    int tx = threadIdx.x & 31, ty = threadIdx.x >> 5;
#pragma unroll
    for (int r = ty; r < 32; r += 8) t[r][tx] = Ws[(size_t)(k0 + r) * N + n0 + tx];
    __syncthreads();
#pragma unroll
    for (int r = ty; r < 32; r += 8) {
        float v = t[tx][r];
        size_t o = (size_t)(n0 + r) * K + k0 + tx;
        u16 hh = f2bf(v);
        Tho[o] = hh;
        Tlo[o] = f2bf(v - bf2f(hh));
    }
}

// ---------------- V transpose: head-major qkv slot [16+h][M][64] -> VT [b][d][s]
__global__ __launch_bounds__(256) void vtrans_kernel(
    const u16* __restrict__ Qh, const u16* __restrict__ Ql,
    u16* __restrict__ VTh, u16* __restrict__ VTl) {
    __shared__ u16 t[64][68];
    int s0 = blockIdx.x * 64;       // seq tile
    int hh = blockIdx.y;            // head
    int b = blockIdx.z & 15, plane = blockIdx.z >> 4;
    const u16* src = (plane ? Ql : Qh) + ((size_t)(16 + hh) * MROWS) * 64;
    u16* dst = (plane ? VTl : VTh);
    int tid = threadIdx.x;
    int rr = tid >> 4, c4 = (tid & 15) * 4;
#pragma unroll
    for (int i = 0; i < 4; ++i) {
        int r = rr + i * 16; // seq within tile
        const u16* p = src + (size_t)(b * SEQ + s0 + r) * 64 + c4;
        *(u16x4*)(&t[r][c4]) = *(const u16x4*)p;
    }
    __syncthreads();
#pragma unroll
    for (int i = 0; i < 4; ++i) {
        int r = rr + i * 16; // d-index within head
        u16x4 v;
        v.x = t[c4 + 0][r]; v.y = t[c4 + 1][r]; v.z = t[c4 + 2][r]; v.w = t[c4 + 3][r];
        *(u16x4*)(dst + (size_t)b * SEQ * DMODEL + (size_t)(hh * 64 + r) * SEQ + s0 + c4) = v;
    }
}

// ------------------------------------------------ elementwise fp32 -> (hi,lo)
__global__ void split_kernel(const float* __restrict__ X, u16* __restrict__ H,
                             u16* __restrict__ L, int n) {
    int i = blockIdx.x * 256 + threadIdx.x;
    if (i < n) {
        float v = X[i];
        u16 hh = f2bf(v);
        H[i] = hh;
        L[i] = f2bf(v - bf2f(hh));
    }
}

// ---------------------------------------- layernorm (+split-K reduce folding)
__global__ __launch_bounds__(256) void ln_kernel(
    const float* __restrict__ X,
    const float* __restrict__ C0, const float* __restrict__ C1,
    const float* __restrict__ bias2, const float* __restrict__ pos2,
    float* __restrict__ Xout,
    float* __restrict__ Y, u16* __restrict__ Yh, u16* __restrict__ Yl,
    const float* __restrict__ g, const float* __restrict__ b) {
    int row  = blockIdx.x * 4 + (threadIdx.x >> 6);
    int lane = threadIdx.x & 63;
    float v[8];
    float s = 0.0f;
#pragma unroll
    for (int j = 0; j < 8; ++j) {
        int d = lane + j * 64;
        size_t o = (size_t)row * DMODEL + d;
        float t = X ? X[o] : 0.0f;
        if (C0)    t += C0[o] + C1[o];
        if (bias2) t += bias2[d];
        if (pos2)  t += pos2[(size_t)(row & (SEQ - 1)) * DMODEL + d];
        v[j] = t;
        if (Xout) Xout[o] = t;
        s += t;
    }
#pragma unroll
    for (int off = 32; off; off >>= 1) s += __shfl_xor(s, off);
    float mu  = s * (1.0f / DMODEL);
    float var = 0.0f;
#pragma unroll
    for (int j = 0; j < 8; ++j) { float d = v[j] - mu; var += d * d; }
#pragma unroll
    for (int off = 32; off; off >>= 1) var += __shfl_xor(var, off);
    float r = rsqrtf(var * (1.0f / DMODEL) + 1e-5f);
#pragma unroll
    for (int j = 0; j < 8; ++j) {
        int d = lane + j * 64;
        float y = (v[j] - mu) * r * g[d] + b[d];
        size_t o = (size_t)row * DMODEL + d;
        if (Y) Y[o] = y;
        if (Yh) {
            u16 hh = f2bf(y);
            Yh[o] = hh;
            Yl[o] = f2bf(y - bf2f(hh));
        }
    }
}

// --------------------------------------------------------- bf16x3 MFMA GEMM
// BK=64, XOR-swizzled LDS (conflict-free frag reads), 96 MFMA per barrier-pair.
// kslice>0: split-K partials -> Cs0/Cs1. qkvscatter: store C head-major.
__global__ __launch_bounds__(256) void gemm3_kernel(
    const u16* __restrict__ Ah, const u16* __restrict__ Al,
    const u16* __restrict__ Bh, const u16* __restrict__ Bl,
    float* __restrict__ Cf, u16* __restrict__ Ch, u16* __restrict__ Cl,
    const float* __restrict__ bias, const float* __restrict__ res,
    const float* __restrict__ pos, int M, int N, int K, int gelu,
    float* __restrict__ Cs0, float* __restrict__ Cs1, int kslice, int qkvscatter) {
    __shared__ __align__(16) u16 AsH[128 * 64];
    __shared__ __align__(16) u16 AsL[128 * 64];
    __shared__ __align__(16) u16 BsH[128 * 64];
    __shared__ __align__(16) u16 BsL[128 * 64];

    int tid  = threadIdx.x;
    int w    = tid >> 6, lane = tid & 63;
    int wr   = w >> 1, wc = w & 1;
    int quad = lane >> 4, l16 = lane & 15;
    int m0   = blockIdx.x * 128;
    int n0   = blockIdx.y * 128;
    int ksA  = (kslice > 0) ? blockIdx.z * kslice : 0;
    int ksB  = (kslice > 0) ? ksA + kslice : K;

    f32x4 acc[4][4];
#pragma unroll
    for (int i = 0; i < 4; ++i)
#pragma unroll
        for (int j = 0; j < 4; ++j) acc[i][j] = (f32x4){0.f, 0.f, 0.f, 0.f};

    int ldsoff[4];
    size_t goff[4];
#pragma unroll
    for (int r = 0; r < 4; ++r) {
        int cidx = tid + 256 * r;
        int row = cidx >> 3;
        int cg = (cidx & 7) ^ (row & 7);
        ldsoff[r] = cidx * 8;
        goff[r] = (size_t)row * K + cg * 8;
    }

    const u16* AbaseH = Ah + (size_t)m0 * K;
    const u16* AbaseL = Al + (size_t)m0 * K;
    const u16* BbaseH = Bh + (size_t)n0 * K;
    const u16* BbaseL = Bl + (size_t)n0 * K;

    for (int ks = ksA; ks < ksB; ks += 64) {
        __syncthreads();
#pragma unroll
        for (int r = 0; r < 4; ++r) {
            size_t g = goff[r] + ks;
            async16(&AsH[ldsoff[r]], AbaseH + g);
            async16(&AsL[ldsoff[r]], AbaseL + g);
            async16(&BsH[ldsoff[r]], BbaseH + g);
            async16(&BsL[ldsoff[r]], BbaseL + g);
        }
        __syncthreads();
#pragma unroll
        for (int s = 0; s < 2; ++s) {
            short8 afh[4], afl[4];
#pragma unroll
            for (int i = 0; i < 4; ++i) {
                int row = wr * 64 + i * 16 + l16;
                int off = row * 64 + (((s << 2) | quad) ^ (row & 7)) * 8;
                afh[i] = *(const short8*)&AsH[off];
                afl[i] = *(const short8*)&AsL[off];
            }
#pragma unroll
            for (int j = 0; j < 4; ++j) {
                int rowb = wc * 64 + j * 16 + l16;
                int offb = rowb * 64 + (((s << 2) | quad) ^ (rowb & 7)) * 8;
                short8 bh = *(const short8*)&BsH[offb];
                short8 bl = *(const short8*)&BsL[offb];
#pragma unroll
                for (int i = 0; i < 4; ++i) {
                    acc[i][j] = __builtin_amdgcn_mfma_f32_16x16x32_bf16(afh[i], bh, acc[i][j], 0, 0, 0);
                    acc[i][j] = __builtin_amdgcn_mfma_f32_16x16x32_bf16(afl[i], bh, acc[i][j], 0, 0, 0);
                    acc[i][j] = __builtin_amdgcn_mfma_f32_16x16x32_bf16(afh[i], bl, acc[i][j], 0, 0, 0);
                }
            }
        }
    }

    float* Cspl = (kslice > 0) ? (blockIdx.z ? Cs1 : Cs0) : nullptr;
    int mbase = m0 + wr * 64;
    int nbase = n0 + wc * 64;
#pragma unroll
    for (int mi = 0; mi < 4; ++mi)
#pragma unroll
        for (int ni = 0; ni < 4; ++ni) {
            f32x4 a = acc[mi][ni];
#pragma unroll
            for (int r = 0; r < 4; ++r) {
                int m = mbase + mi * 16 + quad * 4 + r;
                int n = nbase + ni * 16 + l16;
                float v = a[r];
                size_t o = qkvscatter
                    ? ((size_t)(n >> 6) * M + m) * 64 + (n & 63)
                    : (size_t)m * N + n;
                if (Cspl) { Cspl[o] = v; continue; }
                if (bias) v += bias[n];
                if (pos)  v += pos[(size_t)(m & (SEQ - 1)) * N + n];
                if (res)  v += res[(size_t)m * N + n];
                if (gelu) v = gelu_tanh(v);
                if (Cf) Cf[o] = v;
                if (Ch) {
                    u16 hh = f2bf(v);
                    Ch[o] = hh;
                    Cl[o] = f2bf(v - bf2f(hh));
                }
            }
        }
}

// ------------------------------------------------------------ fp32 GEMM (small)
__global__ __launch_bounds__(256) void gemm_kernel(
    const float* __restrict__ A, const float* __restrict__ Bm,
    float* __restrict__ C, const float* __restrict__ bias,
    int M, int N, int K) {
    __shared__ float As[16][68];
    __shared__ float Bs[16][64];
    int tid = threadIdx.x;
    int tx = tid & 15, ty = tid >> 4;
    int a_m = tid >> 2, a_k = (tid & 3) * 4;
    int b_k = tid >> 4, b_n = (tid & 15) * 4;
    const float* Arow = A + (size_t)(blockIdx.x * 64 + a_m) * K;
    const float* Bcol = Bm + (size_t)blockIdx.y * 64 + b_n;
    float acc[4][4] = {};
    for (int k0 = 0; k0 < K; k0 += 16) {
        float4 av = *(const float4*)(Arow + k0 + a_k);
        float4 bv = *(const float4*)(Bcol + (size_t)(k0 + b_k) * N);
        __syncthreads();
        As[a_k + 0][a_m] = av.x; As[a_k + 1][a_m] = av.y;
        As[a_k + 2][a_m] = av.z; As[a_k + 3][a_m] = av.w;
        *(float4*)(&Bs[b_k][b_n]) = bv;
        __syncthreads();
#pragma unroll
        for (int kk = 0; kk < 16; ++kk) {
            float4 a4 = *(const float4*)(&As[kk][ty * 4]);
            float4 b4 = *(const float4*)(&Bs[kk][tx * 4]);
            float ar[4] = {a4.x, a4.y, a4.z, a4.w};
            float br[4] = {b4.x, b4.y, b4.z, b4.w};
#pragma unroll
            for (int i = 0; i < 4; ++i)
#pragma unroll
                for (int j = 0; j < 4; ++j) acc[i][j] = fmaf(ar[i], br[j], acc[i][j]);
        }
    }
    int m0 = blockIdx.x * 64 + ty * 4;
    int n0 = blockIdx.y * 64 + tx * 4;
#pragma unroll
    for (int i = 0; i < 4; ++i) {
        float vv[4];
#pragma unroll
        for (int j = 0; j < 4; ++j) {
            float t = acc[i][j];
            if (bias) t += bias[n0 + j];
            vv[j] = t;
        }
        *(float4*)(C + (size_t)(m0 + i) * N + n0) = make_float4(vv[0], vv[1], vv[2], vv[3]);
    }
}

// ------------------------------------------- flash attention (STATIC-max softmax)
// ROUND 10: block-cooperative LDS K/V staging. All 4 waves in a block use the
// SAME (bb,hh) K/V — previously each gathered it from global independently
// (4x redundant instrs; each short8 gather touches ~16 half-used 128B lines).
// Now: per kt, 256 threads stage the 64x64 K-tile (hi/lo) + V-tile (hi/lo) =
// 32KB via swizzled async16 (gemm3's exact proven pattern: LDS slot c holds
// global chunk c^(row&7), fetched coalesced), then waves ds_read_b128 frags
// (2-way bank alias = free). Global load-instrs/block/kt: 128 -> 32, line
// touches ~8x down. LDS 49.5KB -> 3 blocks/CU. MFMA + static-max softmax
// math byte-identical to the proven R6 version.
__global__ __launch_bounds__(256) void attn_flash_kernel(
    const u16* __restrict__ QKh, const u16* __restrict__ QKl,
    const u16* __restrict__ VTh, const u16* __restrict__ VTl,
    u16* __restrict__ Oh, u16* __restrict__ Ol) {
    int bh = blockIdx.x & 127;
    int qt = blockIdx.x >> 7;   // 0..7
    int bb = bh >> 3, hh = bh & 7;

    __shared__ __align__(16) float Pw[4][16 * 68]; // wave-private P tiles (17408 B)
    __shared__ __align__(16) u16 KsH[64 * 64];     // 8KB each
    __shared__ __align__(16) u16 KsL[64 * 64];
    __shared__ __align__(16) u16 VsH[64 * 64];
    __shared__ __align__(16) u16 VsL[64 * 64];

    int tid = threadIdx.x;
    int w = tid >> 6, lane = tid & 63;
    int quad = lane >> 4, l16 = lane & 15;
    int qtile = qt * 4 + w;     // 0..31
    float* P = Pw[w];

    const u16* qrh = QKh + ((size_t)hh * MROWS + bb * SEQ + qtile * 16 + l16) * 64 + quad * 8;
    const u16* qrl = QKl + ((size_t)hh * MROWS + bb * SEQ + qtile * 16 + l16) * 64 + quad * 8;
    short8 Qh0 = *(const short8*)qrh;
    short8 Qh1 = *(const short8*)(qrh + 32);
    short8 Ql0 = *(const short8*)qrl;
    short8 Ql1 = *(const short8*)(qrl + 32);

    float lsum[4] = {0.f, 0.f, 0.f, 0.f};   // per-lane partial row sums
    f32x4 acc[4];
#pragma unroll
    for (int dt = 0; dt < 4; ++dt) acc[dt] = (f32x4){0.f, 0.f, 0.f, 0.f};

    const u16* KbH = QKh + ((size_t)(8 + hh) * MROWS + bb * SEQ) * 64;
    const u16* KbL = QKl + ((size_t)(8 + hh) * MROWS + bb * SEQ) * 64;
    const u16* VbH = VTh + (size_t)bb * SEQ * DMODEL + (size_t)(hh * 64) * SEQ;
    const u16* VbL = VTl + (size_t)bb * SEQ * DMODEL + (size_t)(hh * 64) * SEQ;

    // staging map (gemm3 pattern): 512 chunks/plane, 2 per thread per plane.
    // LDS slot cidx holds global chunk (cidx&7)^(row&7) of row=cidx>>3.
    int ldsoff[2];
    int goffK[2];       // K tile: row stride 64 u16
    size_t goffV[2];    // V tile: row stride SEQ u16
#pragma unroll
    for (int r = 0; r < 2; ++r) {
        int cidx = tid + 256 * r;
        int row = cidx >> 3;
        int cg = (cidx & 7) ^ (row & 7);
        ldsoff[r] = cidx * 8;
        goffK[r] = row * 64 + cg * 8;
        goffV[r] = (size_t)row * SEQ + cg * 8;
    }

    for (int kt = 0; kt < 8; ++kt) {
        int kb = kt * 64;
        __syncthreads();   // previous tile fully consumed by all waves
#pragma unroll
        for (int r = 0; r < 2; ++r) {
            async16(&KsH[ldsoff[r]], KbH + (size_t)kb * 64 + goffK[r]);
            async16(&KsL[ldsoff[r]], KbL + (size_t)kb * 64 + goffK[r]);
            async16(&VsH[ldsoff[r]], VbH + kb + goffV[r]);
            async16(&VsL[ldsoff[r]], VbL + kb + goffV[r]);
        }
        __syncthreads();   // staged (compiler drains vmcnt before barrier)

        // ---- QK^T from LDS -> P = exp(score/8), accumulate row sums ----
#pragma unroll
        for (int s = 0; s < 4; ++s) {
            int row = s * 16 + l16;
            int c0 = (quad ^ (row & 7)) * 8;          // chunk quad
            int c1 = ((quad | 4) ^ (row & 7)) * 8;    // chunk quad+4
            f32x4 a = (f32x4){0.f, 0.f, 0.f, 0.f};
            {
                short8 Kh0 = *(const short8*)&KsH[row * 64 + c0];
                short8 Kh1 = *(const short8*)&KsH[row * 64 + c1];
                a = __builtin_amdgcn_mfma_f32_16x16x32_bf16(Qh0, Kh0, a, 0, 0, 0);
                a = __builtin_amdgcn_mfma_f32_16x16x32_bf16(Qh1, Kh1, a, 0, 0, 0);
                a = __builtin_amdgcn_mfma_f32_16x16x32_bf16(Ql0, Kh0, a, 0, 0, 0);
                a = __builtin_amdgcn_mfma_f32_16x16x32_bf16(Ql1, Kh1, a, 0, 0, 0);
            }
            {
                short8 Kl0 = *(const short8*)&KsL[row * 64 + c0];
                short8 Kl1 = *(const short8*)&KsL[row * 64 + c1];
                a = __builtin_amdgcn_mfma_f32_16x16x32_bf16(Qh0, Kl0, a, 0, 0, 0);
                a = __builtin_amdgcn_mfma_f32_16x16x32_bf16(Qh1, Kl1, a, 0, 0, 0);
            }
#pragma unroll
            for (int r = 0; r < 4; ++r) {
                float p = __expf(a[r] * 0.125f);
                lsum[r] += p;
                P[(quad * 4 + r) * 68 + s * 16 + l16] = p;
            }
        }
        // ---- PV from LDS: ks-outer, ph/pl 8 regs live ----
#pragma unroll
        for (int ks = 0; ks < 2; ++ks) {
            short8 ph, pl;
            {
                const float* src = &P[l16 * 68 + ks * 32 + quad * 8];
                f32x4 a0 = *(const f32x4*)src;
                f32x4 a1 = *(const f32x4*)(src + 4);
                float v[8] = {a0[0], a0[1], a0[2], a0[3], a1[0], a1[1], a1[2], a1[3]};
#pragma unroll
                for (int j = 0; j < 8; ++j) {
                    u16 hv = f2bf(v[j]);
                    ph[j] = (short)hv;
                    pl[j] = (short)f2bf(v[j] - bf2f(hv));
                }
            }
#pragma unroll
            for (int dt = 0; dt < 4; ++dt) {
                int rowv = dt * 16 + l16;
                int cv = (((ks << 2) | quad) ^ (rowv & 7)) * 8;
                short8 Vh = *(const short8*)&VsH[rowv * 64 + cv];
                short8 Vl = *(const short8*)&VsL[rowv * 64 + cv];
                acc[dt] = __builtin_amdgcn_mfma_f32_16x16x32_bf16(ph, Vh, acc[dt], 0, 0, 0);
                acc[dt] = __builtin_amdgcn_mfma_f32_16x16x32_bf16(pl, Vh, acc[dt], 0, 0, 0);
                acc[dt] = __builtin_amdgcn_mfma_f32_16x16x32_bf16(ph, Vl, acc[dt], 0, 0, 0);
            }
        }
    }

    // ---- epilogue: single row-sum reduce (within each quad's 16 lanes) ----
#pragma unroll
    for (int r = 0; r < 4; ++r) {
#pragma unroll
        for (int off = 8; off; off >>= 1) lsum[r] += __shfl_xor(lsum[r], off);
    }
#pragma unroll
    for (int r = 0; r < 4; ++r) {
        float inv = 1.0f / lsum[r];
        size_t rowoff = (size_t)(bb * SEQ + qtile * 16 + quad * 4 + r) * DMODEL + hh * 64;
#pragma unroll
        for (int dt = 0; dt < 4; ++dt) {
            float v = acc[dt][r] * inv;
            u16 hv = f2bf(v);
            Oh[rowoff + dt * 16 + l16] = hv;
            Ol[rowoff + dt * 16 + l16] = f2bf(v - bf2f(hv));
        }
    }
}

// ----------------------------------------------------------------- MFMA VQ
// R9 confirmed reg-banking is compiler-defeated (VGPR 52, time unchanged);
// kept as-is (equal to original within noise) to minimize churn.
__global__ __launch_bounds__(256) void vq3_kernel(
    const float* __restrict__ Z, const u16* __restrict__ Zh, const u16* __restrict__ Zl,
    const u16* __restrict__ CBh, const u16* __restrict__ CBl,
    const float* __restrict__ CB, const float* __restrict__ CBN,
    float* __restrict__ out) {
    __shared__ float sbest[4][16];
    __shared__ int sidx[4][16];
    __shared__ int ibest[16];
    __shared__ float psum[4][64];
    __shared__ float cl4[4];

    int tid = threadIdx.x;
    int w = tid >> 6, lane = tid & 63;
    int quad = lane >> 4, l16 = lane & 15;
    int row0 = blockIdx.x * 16;

    const u16* zph = Zh + (size_t)(row0 + l16) * CBD + quad * 8;
    const u16* zpl = Zl + (size_t)(row0 + l16) * CBD + quad * 8;
    short8 Z0h = *(const short8*)zph;
    short8 Z1h = *(const short8*)(zph + 32);
    short8 Z0l = *(const short8*)zpl;
    short8 Z1l = *(const short8*)(zpl + 32);

    float best[4] = {3.4e38f, 3.4e38f, 3.4e38f, 3.4e38f};
    int bidx[4] = {0, 0, 0, 0};

    short8 A0h, A1h, A0l, A1l;  float An;
    short8 B0h, B1h, B0l, B1l;  float Bn;
    short8 C0h, C1h, C0l, C1l;  float Cn;
    short8 D0h, D1h, D0l, D1l;  float Dn;

#define LOADB(bk, cc) {                                            \
    int c_ = (cc);                                                 \
    const u16* ph_ = CBh + (size_t)c_ * CBD + quad * 8;            \
    const u16* pl_ = CBl + (size_t)c_ * CBD + quad * 8;            \
    bk##0h = *(const short8*)ph_;  bk##1h = *(const short8*)(ph_ + 32); \
    bk##0l = *(const short8*)pl_;  bk##1l = *(const short8*)(pl_ + 32); \
    bk##n  = CBN[c_]; }

#define COMPB(bk, cc) {                                                          \
    f32x4 a_ = (f32x4){0.f, 0.f, 0.f, 0.f};                                      \
    int c_ = (cc);                                                               \
    a_ = __builtin_amdgcn_mfma_f32_16x16x32_bf16(Z0h, bk##0h, a_, 0, 0, 0);      \
    a_ = __builtin_amdgcn_mfma_f32_16x16x32_bf16(Z1h, bk##1h, a_, 0, 0, 0);      \
    a_ = __builtin_amdgcn_mfma_f32_16x16x32_bf16(Z0l, bk##0h, a_, 0, 0, 0);      \
    a_ = __builtin_amdgcn_mfma_f32_16x16x32_bf16(Z1l, bk##1h, a_, 0, 0, 0);      \
    a_ = __builtin_amdgcn_mfma_f32_16x16x32_bf16(Z0h, bk##0l, a_, 0, 0, 0);      \
    a_ = __builtin_amdgcn_mfma_f32_16x16x32_bf16(Z1h, bk##1l, a_, 0, 0, 0);      \
    _Pragma("unroll")                                                            \
    for (int r = 0; r < 4; ++r) {                                                \
        float s_ = bk##n - 2.0f * a_[r];                                         \
        if (s_ < best[r]) { best[r] = s_; bidx[r] = c_; }                        \
    } }

    const int NW = CBS / 4;          // 2048 codes per wave
    int cbase = w * NW;
    LOADB(A, cbase + l16);
    LOADB(B, cbase + 16 + l16);
    LOADB(C, cbase + 32 + l16);
    LOADB(D, cbase + 48 + l16);
    for (int t = 0; t < NW; t += 64) {
        COMPB(A, cbase + t + l16);       LOADB(A, cbase + ((t + 64)  & (NW - 1)) + l16);
        COMPB(B, cbase + t + 16 + l16);  LOADB(B, cbase + ((t + 80)  & (NW - 1)) + l16);
        COMPB(C, cbase + t + 32 + l16);  LOADB(C, cbase + ((t + 96)  & (NW - 1)) + l16);
        COMPB(D, cbase + t + 48 + l16);  LOADB(D, cbase + ((t + 112) & (NW - 1)) + l16);
    }

#undef LOADB
#undef COMPB

#pragma unroll
    for (int off = 8; off; off >>= 1) {
#pragma unroll
        for (int r = 0; r < 4; ++r) {
            float ov = __shfl_xor(best[r], off);
            int oi = __shfl_xor(bidx[r], off);
            if (ov < best[r] || (ov == best[r] && oi < bidx[r])) { best[r] = ov; bidx[r] = oi; }
        }
    }
    if (l16 == 0) {
#pragma unroll
        for (int r = 0; r < 4; ++r) {
            sbest[w][quad * 4 + r] = best[r];
            sidx[w][quad * 4 + r] = bidx[r];
        }
    }
    __syncthreads();
    if (tid < 16) {
        float bv = sbest[0][tid];
        int bi = sidx[0][tid];
#pragma unroll
        for (int ww = 1; ww < 4; ++ww) {
            float ov = sbest[ww][tid];
            int oi = sidx[ww][tid];
            if (ov < bv || (ov == bv && oi < bi)) { bv = ov; bi = oi; }
        }
        ibest[tid] = bi;
    }
    __syncthreads();

    int d2 = lane;
    float qacc = 0.0f, closs = 0.0f;
#pragma unroll
    for (int j = 0; j < 4; ++j) {
        int r2 = w * 4 + j;
        int bi = ibest[r2];
        float q = CB[(size_t)bi * CBD + d2];
        float z = Z[(size_t)(row0 + r2) * CBD + d2];
        qacc += q;
        float df = q - z;
        closs += df * df;
    }
    psum[w][d2] = qacc;
#pragma unroll
    for (int off = 32; off; off >>= 1) closs += __shfl_xor(closs, off);
    if (d2 == 0) cl4[w] = closs;
    __syncthreads();
    if (tid < 64) {
        float t = psum[0][tid] + psum[1][tid] + psum[2][tid] + psum[3][tid];
        int b = row0 >> 9;
        atomicAdd(out + b * 64 + tid, t);
    }
    if (tid == 0)
        atomicAdd(out + 1024, (cl4[0] + cl4[1] + cl4[2] + cl4[3]) * (1.0f / (float)(MROWS * CBD)));
}

// -------------------------------------------------------------------- launch
extern "C" void kernel_launch(void* const* d_in, const int* in_sizes, int n_in,
                              void* d_out, int out_size, void* d_ws, size_t ws_size,
                              hipStream_t stream) {
    const float* x    = (const float*)d_in[0];
    const float* w_in = (const float*)d_in[1];
    const float* b_in = (const float*)d_in[2];
    const float* pos  = (const float*)d_in[3];
    const float* ln1g = (const float*)d_in[4];
    const float* ln1b = (const float*)d_in[5];
    const float* wq   = (const float*)d_in[6];
    const float* wk   = (const float*)d_in[7];
    const float* wv   = (const float*)d_in[8];
    const float* wo   = (const float*)d_in[9];
    const float* ln2g = (const float*)d_in[10];
    const float* ln2b = (const float*)d_in[11];
    const float* ffw1 = (const float*)d_in[12];
    const float* ffb1 = (const float*)d_in[13];
    const float* ffw2 = (const float*)d_in[14];
    const float* ffb2 = (const float*)d_in[15];
    const float* lnfg = (const float*)d_in[16];
    const float* lnfb = (const float*)d_in[17];
    const float* wout = (const float*)d_in[18];
    const float* bout = (const float*)d_in[19];
    const float* cb   = (const float*)d_in[20];
    float* out = (float*)d_out;

    const size_t MD  = (size_t)MROWS * DMODEL;   // 4,194,304
    const size_t MQ  = (size_t)MROWS * 1536;     // 12,582,912
    const size_t MF  = (size_t)MROWS * DFF;      // 16,777,216

    float* ws   = (float*)d_ws;
    float* h    = ws;
    float* t0   = h + MD;
    float* big  = t0 + MD;                   // MF floats (aliased region)
    float* zb   = big + MF;
    float* cbn  = zb + (size_t)MROWS * CBD;
    u16* cbh    = (u16*)(cbn + CBS);
    u16* cbl    = cbh + (size_t)CBS * CBD;
    u16* t0h    = (u16*)(cbh + 2 * (size_t)CBS * CBD);
    u16* t0l    = t0h + MD;
    u16* wb     = t0l + MD;

    // big aliases
    u16* qkvh = (u16*)big;
    u16* qkvl = qkvh + MQ;
    u16* obh  = qkvl + MQ;
    u16* obl  = obh + MD;
    u16* xh   = obh;
    u16* xl   = obl;
    u16* fmh  = (u16*)big;
    u16* fml  = fmh + MF;
    u16* zbh  = (u16*)big;        // VQ phase: big region is dead
    u16* zbl  = zbh + (size_t)MROWS * CBD;

    const size_t S_WIN  = (size_t)DMODEL * DMODEL;
    const size_t S_QKV  = (size_t)1536 * DMODEL * NDEPTH;
    const size_t S_WO   = S_WIN * NDEPTH;
    const size_t S_FF1  = (size_t)DFF * DMODEL * NDEPTH;
    const size_t S_FF2  = S_FF1;
    u16* winT_h = wb;
    u16* winT_l = winT_h + S_WIN;
    u16* qkvT_h = winT_l + S_WIN;
    u16* qkvT_l = qkvT_h + S_QKV;
    u16* woT_h  = qkvT_l + S_QKV;
    u16* woT_l  = woT_h + S_WO;
    u16* ff1T_h = woT_l + S_WO;
    u16* ff1T_l = ff1T_h + S_FF1;
    u16* ff2T_h = ff1T_l + S_FF1;
    u16* ff2T_l = ff2T_h + S_FF2;
    u16* VTh = ff2T_l + S_FF2;
    u16* VTl = VTh + (size_t)BATCH * SEQ * DMODEL;
    // split-K partial buffers (fp32, M x 512 each)
    float* spK0 = (float*)(VTl + (size_t)BATCH * SEQ * DMODEL);
    float* spK1 = spK0 + MD;

    dim3 blk(256);

    zero_kernel<<<dim3((out_size + 255) / 256), blk, 0, stream>>>(out, out_size);
    cbn_kernel<<<dim3(CBS / 256), blk, 0, stream>>>(cb, cbn);
    split_kernel<<<dim3((int)(CBS * CBD / 256)), blk, 0, stream>>>(cb, cbh, cbl, CBS * CBD);

    wtrans_kernel<<<dim3(16, 16, 1), blk, 0, stream>>>(w_in, winT_h, winT_l, DMODEL, DMODEL, 0, 0);
    wtrans_kernel<<<dim3(16, 16, NDEPTH), blk, 0, stream>>>(
        wq, qkvT_h, qkvT_l, DMODEL, DMODEL, (long)DMODEL * DMODEL, (long)1536 * DMODEL);
    wtrans_kernel<<<dim3(16, 16, NDEPTH), blk, 0, stream>>>(
        wk, qkvT_h + (size_t)512 * DMODEL, qkvT_l + (size_t)512 * DMODEL,
        DMODEL, DMODEL, (long)DMODEL * DMODEL, (long)1536 * DMODEL);
    wtrans_kernel<<<dim3(16, 16, NDEPTH), blk, 0, stream>>>(
        wv, qkvT_h + (size_t)1024 * DMODEL, qkvT_l + (size_t)1024 * DMODEL,
        DMODEL, DMODEL, (long)DMODEL * DMODEL, (long)1536 * DMODEL);
    wtrans_kernel<<<dim3(16, 16, NDEPTH), blk, 0, stream>>>(
        wo, woT_h, woT_l, DMODEL, DMODEL, (long)DMODEL * DMODEL, (long)DMODEL * DMODEL);
    wtrans_kernel<<<dim3(DFF / 32, 16, NDEPTH), blk, 0, stream>>>(
        ffw1, ff1T_h, ff1T_l, DMODEL, DFF, (long)DMODEL * DFF, (long)DFF * DMODEL);
    wtrans_kernel<<<dim3(16, DFF / 32, NDEPTH), blk, 0, stream>>>(
        ffw2, ff2T_h, ff2T_l, DFF, DMODEL, (long)DFF * DMODEL, (long)DMODEL * DFF);

    split_kernel<<<dim3((int)(MD / 256)), blk, 0, stream>>>(x, xh, xl, (int)MD);

    // input projection: split-K=2 -> spK0/spK1 (reduced+pos+bias inside ln1 of layer 0)
    gemm3_kernel<<<dim3(MROWS / 128, DMODEL / 128, 2), blk, 0, stream>>>(
        xh, xl, winT_h, winT_l, nullptr, nullptr, nullptr, nullptr, nullptr, nullptr,
        MROWS, DMODEL, DMODEL, 0, spK0, spK1, 256, 0);

    for (int l = 0; l < NDEPTH; ++l) {
        // ln1 folds: l==0 -> input proj (+b_in+pos); l>0 -> previous ff2 (+ffb2[l-1])
        ln_kernel<<<dim3(MROWS / 4), blk, 0, stream>>>(
            (l == 0) ? nullptr : h, spK0, spK1,
            (l == 0) ? b_in : (ffb2 + (size_t)(l - 1) * DMODEL),
            (l == 0) ? pos : nullptr, h,
            nullptr, t0h, t0l, ln1g + l * DMODEL, ln1b + l * DMODEL);
        // fused QKV -> head-major split planes (slot = part*8+head, each [M][64])
        gemm3_kernel<<<dim3(MROWS / 128, 1536 / 128, 1), blk, 0, stream>>>(
            t0h, t0l, qkvT_h + (size_t)l * 1536 * DMODEL, qkvT_l + (size_t)l * 1536 * DMODEL,
            nullptr, qkvh, qkvl, nullptr, nullptr, nullptr, MROWS, 1536, DMODEL, 0,
            nullptr, nullptr, 0, 1);
        vtrans_kernel<<<dim3(8, 8, 32), blk, 0, stream>>>(qkvh, qkvl, VTh, VTl);
        attn_flash_kernel<<<dim3(1024), blk, 0, stream>>>(
            qkvh, qkvl, VTh, VTl, obh, obl);
        // wo: split-K=2 (reduced + residual inside ln2)
        gemm3_kernel<<<dim3(MROWS / 128, DMODEL / 128, 2), blk, 0, stream>>>(
            obh, obl, woT_h + (size_t)l * S_WIN, woT_l + (size_t)l * S_WIN,
            nullptr, nullptr, nullptr, nullptr, nullptr, nullptr,
            MROWS, DMODEL, DMODEL, 0, spK0, spK1, 256, 0);
        ln_kernel<<<dim3(MROWS / 4), blk, 0, stream>>>(
            h, spK0, spK1, nullptr, nullptr, h,
            nullptr, t0h, t0l, ln2g + l * DMODEL, ln2b + l * DMODEL);
        gemm3_kernel<<<dim3(MROWS / 128, DFF / 128, 1), blk, 0, stream>>>(
            t0h, t0l, ff1T_h + (size_t)l * DFF * DMODEL, ff1T_l + (size_t)l * DFF * DMODEL,
            nullptr, fmh, fml, ffb1 + l * DFF, nullptr, nullptr, MROWS, DFF, DMODEL, 1,
            nullptr, nullptr, 0, 0);
        // ff2: split-K=2 over K=2048 (reduced + ffb2 + residual in next ln1/lnf)
        gemm3_kernel<<<dim3(MROWS / 128, DMODEL / 128, 2), blk, 0, stream>>>(
            fmh, fml, ff2T_h + (size_t)l * DFF * DMODEL, ff2T_l + (size_t)l * DFF * DMODEL,
            nullptr, nullptr, nullptr, nullptr, nullptr, nullptr,
            MROWS, DMODEL, DFF, 0, spK0, spK1, 1024, 0);
    }

    // final ln folds last ff2 (+ffb2[3]); writes fp32 t0 for the out-projection
    ln_kernel<<<dim3(MROWS / 4), blk, 0, stream>>>(
        h, spK0, spK1, ffb2 + (size_t)3 * DMODEL, nullptr, nullptr,
        t0, nullptr, nullptr, lnfg, lnfb);
    gemm_kernel<<<dim3(MROWS / 64, 1), blk, 0, stream>>>(t0, wout, zb, bout, MROWS, CBD, DMODEL);
    split_kernel<<<dim3((int)((size_t)MROWS * CBD / 256)), blk, 0, stream>>>(
        zb, zbh, zbl, MROWS * CBD);
    vq3_kernel<<<dim3(MROWS / 16), blk, 0, stream>>>(zb, zbh, zbl, cbh, cbl, cb, cbn, out);
}

// Round 11
// 1481.308 us; speedup vs baseline: 1.2664x; 1.0220x over previous
//
#include <hip/hip_runtime.h>
#include <cmath>

#define BATCH 16
#define SEQ 512
#define DMODEL 512
#define NDEPTH 4
#define NHEADS 8
#define DHEAD 64
#define DFF 2048
#define CBD 64
#define CBS 8192
#define MROWS (BATCH * SEQ) // 8192

typedef unsigned short u16;
typedef __attribute__((ext_vector_type(8))) short short8; // 8 bf16 = 4 VGPRs (MFMA A/B frag)
typedef __attribute__((ext_vector_type(4))) float f32x4;  // MFMA C/D frag
typedef __attribute__((ext_vector_type(4))) unsigned short u16x4;

// ---------------------------------------------------------------- bf16 helpers
__device__ __forceinline__ u16 f2bf(float f) {
    unsigned u = __float_as_uint(f);
    u += 0x7fff + ((u >> 16) & 1); // RNE
    return (u16)(u >> 16);
}
__device__ __forceinline__ float bf2f(u16 h) {
    return __uint_as_float(((unsigned)h) << 16);
}

// async global->LDS 16B: LDS dest must be wave-uniform base + lane*16
__device__ __forceinline__ void async16(u16* lds, const u16* g) {
    __builtin_amdgcn_global_load_lds(
        (const __attribute__((address_space(1))) unsigned int*)g,
        (__attribute__((address_space(3))) unsigned int*)lds, 16, 0, 0);
}

// gelu(u) = 0.5u(1+tanh(y)) = u*sigmoid(2y) — exp-form, __expf -> v_exp_f32
__device__ __forceinline__ float gelu_tanh(float u) {
    float t = fmaf(0.07135481627f * u, u * u, 1.5957691216f * u);
    return u / (1.0f + __expf(-t));
}

// ---------------------------------------------------------------- zero output
__global__ void zero_kernel(float* __restrict__ p, int n) {
    int i = blockIdx.x * 256 + threadIdx.x;
    if (i < n) p[i] = 0.0f;
}

// ------------------------------------------------------------- codebook norms
__global__ void cbn_kernel(const float* __restrict__ cb, float* __restrict__ cbn) {
    int c = blockIdx.x * 256 + threadIdx.x;
    if (c >= CBS) return;
    const float* row = cb + (size_t)c * CBD;
    float s = 0.0f;
#pragma unroll
    for (int d = 0; d < CBD; ++d) s += row[d] * row[d];
    cbn[c] = s;
}

// ------------------------- weight transpose + split: W [z][K][N] -> T [z][N][K]
__global__ __launch_bounds__(256) void wtrans_kernel(
    const float* __restrict__ W, u16* __restrict__ Th, u16* __restrict__ Tl,
    int K, int N, long inLS, long outLS) {
    __shared__ float t[32][33];
    const float* Ws = W + (size_t)blockIdx.z * inLS;
    u16* Tho = Th + (size_t)blockIdx.z * outLS;
    u16* Tlo = Tl + (size_t)blockIdx.z * outLS;
    int n0 = blockIdx.x * 32, k0 = blockIdx.y * 32;
    int tx = threadIdx.x & 31, ty = threadIdx.x >> 5;
#pragma unroll
    for (int r = ty; r < 32; r += 8) t[r][tx] = Ws[(size_t)(k0 + r) * N + n0 + tx];
    __syncthreads();
#pragma unroll
    for (int r = ty; r < 32; r += 8) {
        float v = t[tx][r];
        size_t o = (size_t)(n0 + r) * K + k0 + tx;
        u16 hh = f2bf(v);
        Tho[o] = hh;
        Tlo[o] = f2bf(v - bf2f(hh));
    }
}

// ---------------- V transpose: head-major qkv slot [16+h][M][64] -> VT [b][d][s]
__global__ __launch_bounds__(256) void vtrans_kernel(
    const u16* __restrict__ Qh, const u16* __restrict__ Ql,
    u16* __restrict__ VTh, u16* __restrict__ VTl) {
    __shared__ u16 t[64][68];
    int s0 = blockIdx.x * 64;       // seq tile
    int hh = blockIdx.y;            // head
    int b = blockIdx.z & 15, plane = blockIdx.z >> 4;
    const u16* src = (plane ? Ql : Qh) + ((size_t)(16 + hh) * MROWS) * 64;
    u16* dst = (plane ? VTl : VTh);
    int tid = threadIdx.x;
    int rr = tid >> 4, c4 = (tid & 15) * 4;
#pragma unroll
    for (int i = 0; i < 4; ++i) {
        int r = rr + i * 16; // seq within tile
        const u16* p = src + (size_t)(b * SEQ + s0 + r) * 64 + c4;
        *(u16x4*)(&t[r][c4]) = *(const u16x4*)p;
    }
    __syncthreads();
#pragma unroll
    for (int i = 0; i < 4; ++i) {
        int r = rr + i * 16; // d-index within head
        u16x4 v;
        v.x = t[c4 + 0][r]; v.y = t[c4 + 1][r]; v.z = t[c4 + 2][r]; v.w = t[c4 + 3][r];
        *(u16x4*)(dst + (size_t)b * SEQ * DMODEL + (size_t)(hh * 64 + r) * SEQ + s0 + c4) = v;
    }
}

// ------------------------------------------------ elementwise fp32 -> (hi,lo)
__global__ void split_kernel(const float* __restrict__ X, u16* __restrict__ H,
                             u16* __restrict__ L, int n) {
    int i = blockIdx.x * 256 + threadIdx.x;
    if (i < n) {
        float v = X[i];
        u16 hh = f2bf(v);
        H[i] = hh;
        L[i] = f2bf(v - bf2f(hh));
    }
}

// ---------------------------------------- layernorm (+split-K reduce folding)
__global__ __launch_bounds__(256) void ln_kernel(
    const float* __restrict__ X,
    const float* __restrict__ C0, const float* __restrict__ C1,
    const float* __restrict__ bias2, const float* __restrict__ pos2,
    float* __restrict__ Xout,
    float* __restrict__ Y, u16* __restrict__ Yh, u16* __restrict__ Yl,
    const float* __restrict__ g, const float* __restrict__ b) {
    int row  = blockIdx.x * 4 + (threadIdx.x >> 6);
    int lane = threadIdx.x & 63;
    float v[8];
    float s = 0.0f;
#pragma unroll
    for (int j = 0; j < 8; ++j) {
        int d = lane + j * 64;
        size_t o = (size_t)row * DMODEL + d;
        float t = X ? X[o] : 0.0f;
        if (C0)    t += C0[o] + C1[o];
        if (bias2) t += bias2[d];
        if (pos2)  t += pos2[(size_t)(row & (SEQ - 1)) * DMODEL + d];
        v[j] = t;
        if (Xout) Xout[o] = t;
        s += t;
    }
#pragma unroll
    for (int off = 32; off; off >>= 1) s += __shfl_xor(s, off);
    float mu  = s * (1.0f / DMODEL);
    float var = 0.0f;
#pragma unroll
    for (int j = 0; j < 8; ++j) { float d = v[j] - mu; var += d * d; }
#pragma unroll
    for (int off = 32; off; off >>= 1) var += __shfl_xor(var, off);
    float r = rsqrtf(var * (1.0f / DMODEL) + 1e-5f);
#pragma unroll
    for (int j = 0; j < 8; ++j) {
        int d = lane + j * 64;
        float y = (v[j] - mu) * r * g[d] + b[d];
        size_t o = (size_t)row * DMODEL + d;
        if (Y) Y[o] = y;
        if (Yh) {
            u16 hh = f2bf(y);
            Yh[o] = hh;
            Yl[o] = f2bf(y - bf2f(hh));
        }
    }
}

// --------------------------------------------------------- bf16x3 MFMA GEMM
// BK=64, XOR-swizzled LDS (conflict-free frag reads), 96 MFMA per barrier-pair.
// kslice>0: split-K partials -> Cs0/Cs1. qkvscatter: store C head-major.
__global__ __launch_bounds__(256) void gemm3_kernel(
    const u16* __restrict__ Ah, const u16* __restrict__ Al,
    const u16* __restrict__ Bh, const u16* __restrict__ Bl,
    float* __restrict__ Cf, u16* __restrict__ Ch, u16* __restrict__ Cl,
    const float* __restrict__ bias, const float* __restrict__ res,
    const float* __restrict__ pos, int M, int N, int K, int gelu,
    float* __restrict__ Cs0, float* __restrict__ Cs1, int kslice, int qkvscatter) {
    __shared__ __align__(16) u16 AsH[128 * 64];
    __shared__ __align__(16) u16 AsL[128 * 64];
    __shared__ __align__(16) u16 BsH[128 * 64];
    __shared__ __align__(16) u16 BsL[128 * 64];

    int tid  = threadIdx.x;
    int w    = tid >> 6, lane = tid & 63;
    int wr   = w >> 1, wc = w & 1;
    int quad = lane >> 4, l16 = lane & 15;
    int m0   = blockIdx.x * 128;
    int n0   = blockIdx.y * 128;
    int ksA  = (kslice > 0) ? blockIdx.z * kslice : 0;
    int ksB  = (kslice > 0) ? ksA + kslice : K;

    f32x4 acc[4][4];
#pragma unroll
    for (int i = 0; i < 4; ++i)
#pragma unroll
        for (int j = 0; j < 4; ++j) acc[i][j] = (f32x4){0.f, 0.f, 0.f, 0.f};

    int ldsoff[4];
    size_t goff[4];
#pragma unroll
    for (int r = 0; r < 4; ++r) {
        int cidx = tid + 256 * r;
        int row = cidx >> 3;
        int cg = (cidx & 7) ^ (row & 7);
        ldsoff[r] = cidx * 8;
        goff[r] = (size_t)row * K + cg * 8;
    }

    const u16* AbaseH = Ah + (size_t)m0 * K;
    const u16* AbaseL = Al + (size_t)m0 * K;
    const u16* BbaseH = Bh + (size_t)n0 * K;
    const u16* BbaseL = Bl + (size_t)n0 * K;

    for (int ks = ksA; ks < ksB; ks += 64) {
        __syncthreads();
#pragma unroll
        for (int r = 0; r < 4; ++r) {
            size_t g = goff[r] + ks;
            async16(&AsH[ldsoff[r]], AbaseH + g);
            async16(&AsL[ldsoff[r]], AbaseL + g);
            async16(&BsH[ldsoff[r]], BbaseH + g);
            async16(&BsL[ldsoff[r]], BbaseL + g);
        }
        __syncthreads();
#pragma unroll
        for (int s = 0; s < 2; ++s) {
            short8 afh[4], afl[4];
#pragma unroll
            for (int i = 0; i < 4; ++i) {
                int row = wr * 64 + i * 16 + l16;
                int off = row * 64 + (((s << 2) | quad) ^ (row & 7)) * 8;
                afh[i] = *(const short8*)&AsH[off];
                afl[i] = *(const short8*)&AsL[off];
            }
#pragma unroll
            for (int j = 0; j < 4; ++j) {
                int rowb = wc * 64 + j * 16 + l16;
                int offb = rowb * 64 + (((s << 2) | quad) ^ (rowb & 7)) * 8;
                short8 bh = *(const short8*)&BsH[offb];
                short8 bl = *(const short8*)&BsL[offb];
#pragma unroll
                for (int i = 0; i < 4; ++i) {
                    acc[i][j] = __builtin_amdgcn_mfma_f32_16x16x32_bf16(afh[i], bh, acc[i][j], 0, 0, 0);
                    acc[i][j] = __builtin_amdgcn_mfma_f32_16x16x32_bf16(afl[i], bh, acc[i][j], 0, 0, 0);
                    acc[i][j] = __builtin_amdgcn_mfma_f32_16x16x32_bf16(afh[i], bl, acc[i][j], 0, 0, 0);
                }
            }
        }
    }

    float* Cspl = (kslice > 0) ? (blockIdx.z ? Cs1 : Cs0) : nullptr;
    int mbase = m0 + wr * 64;
    int nbase = n0 + wc * 64;
#pragma unroll
    for (int mi = 0; mi < 4; ++mi)
#pragma unroll
        for (int ni = 0; ni < 4; ++ni) {
            f32x4 a = acc[mi][ni];
#pragma unroll
            for (int r = 0; r < 4; ++r) {
                int m = mbase + mi * 16 + quad * 4 + r;
                int n = nbase + ni * 16 + l16;
                float v = a[r];
                size_t o = qkvscatter
                    ? ((size_t)(n >> 6) * M + m) * 64 + (n & 63)
                    : (size_t)m * N + n;
                if (Cspl) { Cspl[o] = v; continue; }
                if (bias) v += bias[n];
                if (pos)  v += pos[(size_t)(m & (SEQ - 1)) * N + n];
                if (res)  v += res[(size_t)m * N + n];
                if (gelu) v = gelu_tanh(v);
                if (Cf) Cf[o] = v;
                if (Ch) {
                    u16 hh = f2bf(v);
                    Ch[o] = hh;
                    Cl[o] = f2bf(v - bf2f(hh));
                }
            }
        }
}

// ------------------------------------------------------------ fp32 GEMM (small)
__global__ __launch_bounds__(256) void gemm_kernel(
    const float* __restrict__ A, const float* __restrict__ Bm,
    float* __restrict__ C, const float* __restrict__ bias,
    int M, int N, int K) {
    __shared__ float As[16][68];
    __shared__ float Bs[16][64];
    int tid = threadIdx.x;
    int tx = tid & 15, ty = tid >> 4;
    int a_m = tid >> 2, a_k = (tid & 3) * 4;
    int b_k = tid >> 4, b_n = (tid & 15) * 4;
    const float* Arow = A + (size_t)(blockIdx.x * 64 + a_m) * K;
    const float* Bcol = Bm + (size_t)blockIdx.y * 64 + b_n;
    float acc[4][4] = {};
    for (int k0 = 0; k0 < K; k0 += 16) {
        float4 av = *(const float4*)(Arow + k0 + a_k);
        float4 bv = *(const float4*)(Bcol + (size_t)(k0 + b_k) * N);
        __syncthreads();
        As[a_k + 0][a_m] = av.x; As[a_k + 1][a_m] = av.y;
        As[a_k + 2][a_m] = av.z; As[a_k + 3][a_m] = av.w;
        *(float4*)(&Bs[b_k][b_n]) = bv;
        __syncthreads();
#pragma unroll
        for (int kk = 0; kk < 16; ++kk) {
            float4 a4 = *(const float4*)(&As[kk][ty * 4]);
            float4 b4 = *(const float4*)(&Bs[kk][tx * 4]);
            float ar[4] = {a4.x, a4.y, a4.z, a4.w};
            float br[4] = {b4.x, b4.y, b4.z, b4.w};
#pragma unroll
            for (int i = 0; i < 4; ++i)
#pragma unroll
                for (int j = 0; j < 4; ++j) acc[i][j] = fmaf(ar[i], br[j], acc[i][j]);
        }
    }
    int m0 = blockIdx.x * 64 + ty * 4;
    int n0 = blockIdx.y * 64 + tx * 4;
#pragma unroll
    for (int i = 0; i < 4; ++i) {
        float vv[4];
#pragma unroll
        for (int j = 0; j < 4; ++j) {
            float t = acc[i][j];
            if (bias) t += bias[n0 + j];
            vv[j] = t;
        }
        *(float4*)(C + (size_t)(m0 + i) * N + n0) = make_float4(vv[0], vv[1], vv[2], vv[3]);
    }
}

// ------------------------------------------- flash attention (STATIC-max softmax)
// R10 WINNER (~51us): block-cooperative LDS K/V staging via swizzled async16
// (global load-instrs/block/kt 128 -> 32, full-line coalescing, no VGPR
// round-trip). Static-max softmax. Kept byte-identical.
__global__ __launch_bounds__(256) void attn_flash_kernel(
    const u16* __restrict__ QKh, const u16* __restrict__ QKl,
    const u16* __restrict__ VTh, const u16* __restrict__ VTl,
    u16* __restrict__ Oh, u16* __restrict__ Ol) {
    int bh = blockIdx.x & 127;
    int qt = blockIdx.x >> 7;   // 0..7
    int bb = bh >> 3, hh = bh & 7;

    __shared__ __align__(16) float Pw[4][16 * 68]; // wave-private P tiles (17408 B)
    __shared__ __align__(16) u16 KsH[64 * 64];     // 8KB each
    __shared__ __align__(16) u16 KsL[64 * 64];
    __shared__ __align__(16) u16 VsH[64 * 64];
    __shared__ __align__(16) u16 VsL[64 * 64];

    int tid = threadIdx.x;
    int w = tid >> 6, lane = tid & 63;
    int quad = lane >> 4, l16 = lane & 15;
    int qtile = qt * 4 + w;     // 0..31
    float* P = Pw[w];

    const u16* qrh = QKh + ((size_t)hh * MROWS + bb * SEQ + qtile * 16 + l16) * 64 + quad * 8;
    const u16* qrl = QKl + ((size_t)hh * MROWS + bb * SEQ + qtile * 16 + l16) * 64 + quad * 8;
    short8 Qh0 = *(const short8*)qrh;
    short8 Qh1 = *(const short8*)(qrh + 32);
    short8 Ql0 = *(const short8*)qrl;
    short8 Ql1 = *(const short8*)(qrl + 32);

    float lsum[4] = {0.f, 0.f, 0.f, 0.f};   // per-lane partial row sums
    f32x4 acc[4];
#pragma unroll
    for (int dt = 0; dt < 4; ++dt) acc[dt] = (f32x4){0.f, 0.f, 0.f, 0.f};

    const u16* KbH = QKh + ((size_t)(8 + hh) * MROWS + bb * SEQ) * 64;
    const u16* KbL = QKl + ((size_t)(8 + hh) * MROWS + bb * SEQ) * 64;
    const u16* VbH = VTh + (size_t)bb * SEQ * DMODEL + (size_t)(hh * 64) * SEQ;
    const u16* VbL = VTl + (size_t)bb * SEQ * DMODEL + (size_t)(hh * 64) * SEQ;

    // staging map (gemm3 pattern): 512 chunks/plane, 2 per thread per plane.
    // LDS slot cidx holds global chunk (cidx&7)^(row&7) of row=cidx>>3.
    int ldsoff[2];
    int goffK[2];       // K tile: row stride 64 u16
    size_t goffV[2];    // V tile: row stride SEQ u16
#pragma unroll
    for (int r = 0; r < 2; ++r) {
        int cidx = tid + 256 * r;
        int row = cidx >> 3;
        int cg = (cidx & 7) ^ (row & 7);
        ldsoff[r] = cidx * 8;
        goffK[r] = row * 64 + cg * 8;
        goffV[r] = (size_t)row * SEQ + cg * 8;
    }

    for (int kt = 0; kt < 8; ++kt) {
        int kb = kt * 64;
        __syncthreads();   // previous tile fully consumed by all waves
#pragma unroll
        for (int r = 0; r < 2; ++r) {
            async16(&KsH[ldsoff[r]], KbH + (size_t)kb * 64 + goffK[r]);
            async16(&KsL[ldsoff[r]], KbL + (size_t)kb * 64 + goffK[r]);
            async16(&VsH[ldsoff[r]], VbH + kb + goffV[r]);
            async16(&VsL[ldsoff[r]], VbL + kb + goffV[r]);
        }
        __syncthreads();   // staged (compiler drains vmcnt before barrier)

        // ---- QK^T from LDS -> P = exp(score/8), accumulate row sums ----
#pragma unroll
        for (int s = 0; s < 4; ++s) {
            int row = s * 16 + l16;
            int c0 = (quad ^ (row & 7)) * 8;          // chunk quad
            int c1 = ((quad | 4) ^ (row & 7)) * 8;    // chunk quad+4
            f32x4 a = (f32x4){0.f, 0.f, 0.f, 0.f};
            {
                short8 Kh0 = *(const short8*)&KsH[row * 64 + c0];
                short8 Kh1 = *(const short8*)&KsH[row * 64 + c1];
                a = __builtin_amdgcn_mfma_f32_16x16x32_bf16(Qh0, Kh0, a, 0, 0, 0);
                a = __builtin_amdgcn_mfma_f32_16x16x32_bf16(Qh1, Kh1, a, 0, 0, 0);
                a = __builtin_amdgcn_mfma_f32_16x16x32_bf16(Ql0, Kh0, a, 0, 0, 0);
                a = __builtin_amdgcn_mfma_f32_16x16x32_bf16(Ql1, Kh1, a, 0, 0, 0);
            }
            {
                short8 Kl0 = *(const short8*)&KsL[row * 64 + c0];
                short8 Kl1 = *(const short8*)&KsL[row * 64 + c1];
                a = __builtin_amdgcn_mfma_f32_16x16x32_bf16(Qh0, Kl0, a, 0, 0, 0);
                a = __builtin_amdgcn_mfma_f32_16x16x32_bf16(Qh1, Kl1, a, 0, 0, 0);
            }
#pragma unroll
            for (int r = 0; r < 4; ++r) {
                float p = __expf(a[r] * 0.125f);
                lsum[r] += p;
                P[(quad * 4 + r) * 68 + s * 16 + l16] = p;
            }
        }
        // ---- PV from LDS: ks-outer, ph/pl 8 regs live ----
#pragma unroll
        for (int ks = 0; ks < 2; ++ks) {
            short8 ph, pl;
            {
                const float* src = &P[l16 * 68 + ks * 32 + quad * 8];
                f32x4 a0 = *(const f32x4*)src;
                f32x4 a1 = *(const f32x4*)(src + 4);
                float v[8] = {a0[0], a0[1], a0[2], a0[3], a1[0], a1[1], a1[2], a1[3]};
#pragma unroll
                for (int j = 0; j < 8; ++j) {
                    u16 hv = f2bf(v[j]);
                    ph[j] = (short)hv;
                    pl[j] = (short)f2bf(v[j] - bf2f(hv));
                }
            }
#pragma unroll
            for (int dt = 0; dt < 4; ++dt) {
                int rowv = dt * 16 + l16;
                int cv = (((ks << 2) | quad) ^ (rowv & 7)) * 8;
                short8 Vh = *(const short8*)&VsH[rowv * 64 + cv];
                short8 Vl = *(const short8*)&VsL[rowv * 64 + cv];
                acc[dt] = __builtin_amdgcn_mfma_f32_16x16x32_bf16(ph, Vh, acc[dt], 0, 0, 0);
                acc[dt] = __builtin_amdgcn_mfma_f32_16x16x32_bf16(pl, Vh, acc[dt], 0, 0, 0);
                acc[dt] = __builtin_amdgcn_mfma_f32_16x16x32_bf16(ph, Vl, acc[dt], 0, 0, 0);
            }
        }
    }

    // ---- epilogue: single row-sum reduce (within each quad's 16 lanes) ----
#pragma unroll
    for (int r = 0; r < 4; ++r) {
#pragma unroll
        for (int off = 8; off; off >>= 1) lsum[r] += __shfl_xor(lsum[r], off);
    }
#pragma unroll
    for (int r = 0; r < 4; ++r) {
        float inv = 1.0f / lsum[r];
        size_t rowoff = (size_t)(bb * SEQ + qtile * 16 + quad * 4 + r) * DMODEL + hh * 64;
#pragma unroll
        for (int dt = 0; dt < 4; ++dt) {
            float v = acc[dt][r] * inv;
            u16 hv = f2bf(v);
            Oh[rowoff + dt * 16 + l16] = hv;
            Ol[rowoff + dt * 16 + l16] = f2bf(v - bf2f(hv));
        }
    }
}

// ----------------------------------------------------------------- MFMA VQ
// ROUND 11: port the R10 attention win to vq3 — block-cooperative LDS staging
// of the codebook. Per 64-code tile: 256 threads stage CBh+CBl (16KB) via
// swizzled async16 (coalesced full lines, no VGPR round-trip — the mechanism
// R10 proved is worth 2.5x vs per-wave register gathers, which R9 showed the
// compiler serializes). Wave w computes codes t + w*16 + l16 from LDS
// (ds_read_b128, 2-way bank alias = free). Per-lane code sequence ascending
// over t -> strict-less keeps first-min-index; cross-lane/wave reduces have
// explicit tie-breaks -> argmin identical.
__global__ __launch_bounds__(256) void vq3_kernel(
    const float* __restrict__ Z, const u16* __restrict__ Zh, const u16* __restrict__ Zl,
    const u16* __restrict__ CBh, const u16* __restrict__ CBl,
    const float* __restrict__ CB, const float* __restrict__ CBN,
    float* __restrict__ out) {
    __shared__ float sbest[4][16];
    __shared__ int sidx[4][16];
    __shared__ int ibest[16];
    __shared__ float psum[4][64];
    __shared__ float cl4[4];
    __shared__ __align__(16) u16 CsH[64 * 64];   // 8KB
    __shared__ __align__(16) u16 CsL[64 * 64];   // 8KB

    int tid = threadIdx.x;
    int w = tid >> 6, lane = tid & 63;
    int quad = lane >> 4, l16 = lane & 15;
    int row0 = blockIdx.x * 16;

    const u16* zph = Zh + (size_t)(row0 + l16) * CBD + quad * 8;
    const u16* zpl = Zl + (size_t)(row0 + l16) * CBD + quad * 8;
    short8 Z0h = *(const short8*)zph;
    short8 Z1h = *(const short8*)(zph + 32);
    short8 Z0l = *(const short8*)zpl;
    short8 Z1l = *(const short8*)(zpl + 32);

    float best[4] = {3.4e38f, 3.4e38f, 3.4e38f, 3.4e38f};
    int bidx[4] = {0, 0, 0, 0};

    // staging map (gemm3/attn pattern): 512 chunks/plane, 2 per thread.
    int ldsoff[2], goffC[2];
#pragma unroll
    for (int r = 0; r < 2; ++r) {
        int cidx = tid + 256 * r;
        int row = cidx >> 3;
        int cg = (cidx & 7) ^ (row & 7);
        ldsoff[r] = cidx * 8;
        goffC[r] = row * 64 + cg * 8;
    }

    int rowc = w * 16 + l16;                     // this wave's code row in tile
    int c0 = (quad ^ (rowc & 7)) * 8;
    int c1 = ((quad | 4) ^ (rowc & 7)) * 8;

    for (int t = 0; t < CBS; t += 64) {
        __syncthreads();   // previous tile consumed by all waves
#pragma unroll
        for (int r = 0; r < 2; ++r) {
            async16(&CsH[ldsoff[r]], CBh + (size_t)t * 64 + goffC[r]);
            async16(&CsL[ldsoff[r]], CBl + (size_t)t * 64 + goffC[r]);
        }
        __syncthreads();   // staged

        int code = t + rowc;
        short8 C0h = *(const short8*)&CsH[rowc * 64 + c0];
        short8 C1h = *(const short8*)&CsH[rowc * 64 + c1];
        short8 C0l = *(const short8*)&CsL[rowc * 64 + c0];
        short8 C1l = *(const short8*)&CsL[rowc * 64 + c1];
        float cn = CBN[code];
        f32x4 a = (f32x4){0.f, 0.f, 0.f, 0.f};
        a = __builtin_amdgcn_mfma_f32_16x16x32_bf16(Z0h, C0h, a, 0, 0, 0);
        a = __builtin_amdgcn_mfma_f32_16x16x32_bf16(Z1h, C1h, a, 0, 0, 0);
        a = __builtin_amdgcn_mfma_f32_16x16x32_bf16(Z0l, C0h, a, 0, 0, 0);
        a = __builtin_amdgcn_mfma_f32_16x16x32_bf16(Z1l, C1h, a, 0, 0, 0);
        a = __builtin_amdgcn_mfma_f32_16x16x32_bf16(Z0h, C0l, a, 0, 0, 0);
        a = __builtin_amdgcn_mfma_f32_16x16x32_bf16(Z1h, C1l, a, 0, 0, 0);
#pragma unroll
        for (int r = 0; r < 4; ++r) {
            float s = cn - 2.0f * a[r];
            if (s < best[r]) { best[r] = s; bidx[r] = code; }
        }
    }

#pragma unroll
    for (int off = 8; off; off >>= 1) {
#pragma unroll
        for (int r = 0; r < 4; ++r) {
            float ov = __shfl_xor(best[r], off);
            int oi = __shfl_xor(bidx[r], off);
            if (ov < best[r] || (ov == best[r] && oi < bidx[r])) { best[r] = ov; bidx[r] = oi; }
        }
    }
    if (l16 == 0) {
#pragma unroll
        for (int r = 0; r < 4; ++r) {
            sbest[w][quad * 4 + r] = best[r];
            sidx[w][quad * 4 + r] = bidx[r];
        }
    }
    __syncthreads();
    if (tid < 16) {
        float bv = sbest[0][tid];
        int bi = sidx[0][tid];
#pragma unroll
        for (int ww = 1; ww < 4; ++ww) {
            float ov = sbest[ww][tid];
            int oi = sidx[ww][tid];
            if (ov < bv || (ov == bv && oi < bi)) { bv = ov; bi = oi; }
        }
        ibest[tid] = bi;
    }
    __syncthreads();

    int d2 = lane;
    float qacc = 0.0f, closs = 0.0f;
#pragma unroll
    for (int j = 0; j < 4; ++j) {
        int r2 = w * 4 + j;
        int bi = ibest[r2];
        float q = CB[(size_t)bi * CBD + d2];
        float z = Z[(size_t)(row0 + r2) * CBD + d2];
        qacc += q;
        float df = q - z;
        closs += df * df;
    }
    psum[w][d2] = qacc;
#pragma unroll
    for (int off = 32; off; off >>= 1) closs += __shfl_xor(closs, off);
    if (d2 == 0) cl4[w] = closs;
    __syncthreads();
    if (tid < 64) {
        float t = psum[0][tid] + psum[1][tid] + psum[2][tid] + psum[3][tid];
        int b = row0 >> 9;
        atomicAdd(out + b * 64 + tid, t);
    }
    if (tid == 0)
        atomicAdd(out + 1024, (cl4[0] + cl4[1] + cl4[2] + cl4[3]) * (1.0f / (float)(MROWS * CBD)));
}

// -------------------------------------------------------------------- launch
extern "C" void kernel_launch(void* const* d_in, const int* in_sizes, int n_in,
                              void* d_out, int out_size, void* d_ws, size_t ws_size,
                              hipStream_t stream) {
    const float* x    = (const float*)d_in[0];
    const float* w_in = (const float*)d_in[1];
    const float* b_in = (const float*)d_in[2];
    const float* pos  = (const float*)d_in[3];
    const float* ln1g = (const float*)d_in[4];
    const float* ln1b = (const float*)d_in[5];
    const float* wq   = (const float*)d_in[6];
    const float* wk   = (const float*)d_in[7];
    const float* wv   = (const float*)d_in[8];
    const float* wo   = (const float*)d_in[9];
    const float* ln2g = (const float*)d_in[10];
    const float* ln2b = (const float*)d_in[11];
    const float* ffw1 = (const float*)d_in[12];
    const float* ffb1 = (const float*)d_in[13];
    const float* ffw2 = (const float*)d_in[14];
    const float* ffb2 = (const float*)d_in[15];
    const float* lnfg = (const float*)d_in[16];
    const float* lnfb = (const float*)d_in[17];
    const float* wout = (const float*)d_in[18];
    const float* bout = (const float*)d_in[19];
    const float* cb   = (const float*)d_in[20];
    float* out = (float*)d_out;

    const size_t MD  = (size_t)MROWS * DMODEL;   // 4,194,304
    const size_t MQ  = (size_t)MROWS * 1536;     // 12,582,912
    const size_t MF  = (size_t)MROWS * DFF;      // 16,777,216

    float* ws   = (float*)d_ws;
    float* h    = ws;
    float* t0   = h + MD;
    float* big  = t0 + MD;                   // MF floats (aliased region)
    float* zb   = big + MF;
    float* cbn  = zb + (size_t)MROWS * CBD;
    u16* cbh    = (u16*)(cbn + CBS);
    u16* cbl    = cbh + (size_t)CBS * CBD;
    u16* t0h    = (u16*)(cbh + 2 * (size_t)CBS * CBD);
    u16* t0l    = t0h + MD;
    u16* wb     = t0l + MD;

    // big aliases
    u16* qkvh = (u16*)big;
    u16* qkvl = qkvh + MQ;
    u16* obh  = qkvl + MQ;
    u16* obl  = obh + MD;
    u16* xh   = obh;
    u16* xl   = obl;
    u16* fmh  = (u16*)big;
    u16* fml  = fmh + MF;
    u16* zbh  = (u16*)big;        // VQ phase: big region is dead
    u16* zbl  = zbh + (size_t)MROWS * CBD;

    const size_t S_WIN  = (size_t)DMODEL * DMODEL;
    const size_t S_QKV  = (size_t)1536 * DMODEL * NDEPTH;
    const size_t S_WO   = S_WIN * NDEPTH;
    const size_t S_FF1  = (size_t)DFF * DMODEL * NDEPTH;
    const size_t S_FF2  = S_FF1;
    u16* winT_h = wb;
    u16* winT_l = winT_h + S_WIN;
    u16* qkvT_h = winT_l + S_WIN;
    u16* qkvT_l = qkvT_h + S_QKV;
    u16* woT_h  = qkvT_l + S_QKV;
    u16* woT_l  = woT_h + S_WO;
    u16* ff1T_h = woT_l + S_WO;
    u16* ff1T_l = ff1T_h + S_FF1;
    u16* ff2T_h = ff1T_l + S_FF1;
    u16* ff2T_l = ff2T_h + S_FF2;
    u16* VTh = ff2T_l + S_FF2;
    u16* VTl = VTh + (size_t)BATCH * SEQ * DMODEL;
    // split-K partial buffers (fp32, M x 512 each)
    float* spK0 = (float*)(VTl + (size_t)BATCH * SEQ * DMODEL);
    float* spK1 = spK0 + MD;

    dim3 blk(256);

    zero_kernel<<<dim3((out_size + 255) / 256), blk, 0, stream>>>(out, out_size);
    cbn_kernel<<<dim3(CBS / 256), blk, 0, stream>>>(cb, cbn);
    split_kernel<<<dim3((int)(CBS * CBD / 256)), blk, 0, stream>>>(cb, cbh, cbl, CBS * CBD);

    wtrans_kernel<<<dim3(16, 16, 1), blk, 0, stream>>>(w_in, winT_h, winT_l, DMODEL, DMODEL, 0, 0);
    wtrans_kernel<<<dim3(16, 16, NDEPTH), blk, 0, stream>>>(
        wq, qkvT_h, qkvT_l, DMODEL, DMODEL, (long)DMODEL * DMODEL, (long)1536 * DMODEL);
    wtrans_kernel<<<dim3(16, 16, NDEPTH), blk, 0, stream>>>(
        wk, qkvT_h + (size_t)512 * DMODEL, qkvT_l + (size_t)512 * DMODEL,
        DMODEL, DMODEL, (long)DMODEL * DMODEL, (long)1536 * DMODEL);
    wtrans_kernel<<<dim3(16, 16, NDEPTH), blk, 0, stream>>>(
        wv, qkvT_h + (size_t)1024 * DMODEL, qkvT_l + (size_t)1024 * DMODEL,
        DMODEL, DMODEL, (long)DMODEL * DMODEL, (long)1536 * DMODEL);
    wtrans_kernel<<<dim3(16, 16, NDEPTH), blk, 0, stream>>>(
        wo, woT_h, woT_l, DMODEL, DMODEL, (long)DMODEL * DMODEL, (long)DMODEL * DMODEL);
    wtrans_kernel<<<dim3(DFF / 32, 16, NDEPTH), blk, 0, stream>>>(
        ffw1, ff1T_h, ff1T_l, DMODEL, DFF, (long)DMODEL * DFF, (long)DFF * DMODEL);
    wtrans_kernel<<<dim3(16, DFF / 32, NDEPTH), blk, 0, stream>>>(
        ffw2, ff2T_h, ff2T_l, DFF, DMODEL, (long)DFF * DMODEL, (long)DMODEL * DFF);

    split_kernel<<<dim3((int)(MD / 256)), blk, 0, stream>>>(x, xh, xl, (int)MD);

    // input projection: split-K=2 -> spK0/spK1 (reduced+pos+bias inside ln1 of layer 0)
    gemm3_kernel<<<dim3(MROWS / 128, DMODEL / 128, 2), blk, 0, stream>>>(
        xh, xl, winT_h, winT_l, nullptr, nullptr, nullptr, nullptr, nullptr, nullptr,
        MROWS, DMODEL, DMODEL, 0, spK0, spK1, 256, 0);

    for (int l = 0; l < NDEPTH; ++l) {
        // ln1 folds: l==0 -> input proj (+b_in+pos); l>0 -> previous ff2 (+ffb2[l-1])
        ln_kernel<<<dim3(MROWS / 4), blk, 0, stream>>>(
            (l == 0) ? nullptr : h, spK0, spK1,
            (l == 0) ? b_in : (ffb2 + (size_t)(l - 1) * DMODEL),
            (l == 0) ? pos : nullptr, h,
            nullptr, t0h, t0l, ln1g + l * DMODEL, ln1b + l * DMODEL);
        // fused QKV -> head-major split planes (slot = part*8+head, each [M][64])
        gemm3_kernel<<<dim3(MROWS / 128, 1536 / 128, 1), blk, 0, stream>>>(
            t0h, t0l, qkvT_h + (size_t)l * 1536 * DMODEL, qkvT_l + (size_t)l * 1536 * DMODEL,
            nullptr, qkvh, qkvl, nullptr, nullptr, nullptr, MROWS, 1536, DMODEL, 0,
            nullptr, nullptr, 0, 1);
        vtrans_kernel<<<dim3(8, 8, 32), blk, 0, stream>>>(qkvh, qkvl, VTh, VTl);
        attn_flash_kernel<<<dim3(1024), blk, 0, stream>>>(
            qkvh, qkvl, VTh, VTl, obh, obl);
        // wo: split-K=2 (reduced + residual inside ln2)
        gemm3_kernel<<<dim3(MROWS / 128, DMODEL / 128, 2), blk, 0, stream>>>(
            obh, obl, woT_h + (size_t)l * S_WIN, woT_l + (size_t)l * S_WIN,
            nullptr, nullptr, nullptr, nullptr, nullptr, nullptr,
            MROWS, DMODEL, DMODEL, 0, spK0, spK1, 256, 0);
        ln_kernel<<<dim3(MROWS / 4), blk, 0, stream>>>(
            h, spK0, spK1, nullptr, nullptr, h,
            nullptr, t0h, t0l, ln2g + l * DMODEL, ln2b + l * DMODEL);
        gemm3_kernel<<<dim3(MROWS / 128, DFF / 128, 1), blk, 0, stream>>>(
            t0h, t0l, ff1T_h + (size_t)l * DFF * DMODEL, ff1T_l + (size_t)l * DFF * DMODEL,
            nullptr, fmh, fml, ffb1 + l * DFF, nullptr, nullptr, MROWS, DFF, DMODEL, 1,
            nullptr, nullptr, 0, 0);
        // ff2: split-K=2 over K=2048 (reduced + ffb2 + residual in next ln1/lnf)
        gemm3_kernel<<<dim3(MROWS / 128, DMODEL / 128, 2), blk, 0, stream>>>(
            fmh, fml, ff2T_h + (size_t)l * DFF * DMODEL, ff2T_l + (size_t)l * DFF * DMODEL,
            nullptr, nullptr, nullptr, nullptr, nullptr, nullptr,
            MROWS, DMODEL, DFF, 0, spK0, spK1, 1024, 0);
    }

    // final ln folds last ff2 (+ffb2[3]); writes fp32 t0 for the out-projection
    ln_kernel<<<dim3(MROWS / 4), blk, 0, stream>>>(
        h, spK0, spK1, ffb2 + (size_t)3 * DMODEL, nullptr, nullptr,
        t0, nullptr, nullptr, lnfg, lnfb);
    gemm_kernel<<<dim3(MROWS / 64, 1), blk, 0, stream>>>(t0, wout, zb, bout, MROWS, CBD, DMODEL);
    split_kernel<<<dim3((int)((size_t)MROWS * CBD / 256)), blk, 0, stream>>>(
        zb, zbh, zbl, MROWS * CBD);
    vq3_kernel<<<dim3(MROWS / 16), blk, 0, stream>>>(zb, zbh, zbl, cbh, cbl, cb, cbn, out);
}

// Round 12
// 1471.646 us; speedup vs baseline: 1.2747x; 1.0066x over previous
//
#include <hip/hip_runtime.h>
#include <cmath>

#define BATCH 16
#define SEQ 512
#define DMODEL 512
#define NDEPTH 4
#define NHEADS 8
#define DHEAD 64
#define DFF 2048
#define CBD 64
#define CBS 8192
#define MROWS (BATCH * SEQ) // 8192

typedef unsigned short u16;
typedef __attribute__((ext_vector_type(8))) short short8; // 8 bf16 = 4 VGPRs (MFMA A/B frag)
typedef __attribute__((ext_vector_type(4))) float f32x4;  // MFMA C/D frag
typedef __attribute__((ext_vector_type(4))) unsigned short u16x4;

// ---------------------------------------------------------------- bf16 helpers
__device__ __forceinline__ u16 f2bf(float f) {
    unsigned u = __float_as_uint(f);
    u += 0x7fff + ((u >> 16) & 1); // RNE
    return (u16)(u >> 16);
}
__device__ __forceinline__ float bf2f(u16 h) {
    return __uint_as_float(((unsigned)h) << 16);
}

// async global->LDS 16B: LDS dest must be wave-uniform base + lane*16
__device__ __forceinline__ void async16(u16* lds, const u16* g) {
    __builtin_amdgcn_global_load_lds(
        (const __attribute__((address_space(1))) unsigned int*)g,
        (__attribute__((address_space(3))) unsigned int*)lds, 16, 0, 0);
}

// gelu(u) = 0.5u(1+tanh(y)) = u*sigmoid(2y) — exp-form, __expf -> v_exp_f32
__device__ __forceinline__ float gelu_tanh(float u) {
    float t = fmaf(0.07135481627f * u, u * u, 1.5957691216f * u);
    return u / (1.0f + __expf(-t));
}

// ---------------------------------------------------------------- zero output
__global__ void zero_kernel(float* __restrict__ p, int n) {
    int i = blockIdx.x * 256 + threadIdx.x;
    if (i < n) p[i] = 0.0f;
}

// ------------------------------------------------------------- codebook norms
__global__ void cbn_kernel(const float* __restrict__ cb, float* __restrict__ cbn) {
    int c = blockIdx.x * 256 + threadIdx.x;
    if (c >= CBS) return;
    const float* row = cb + (size_t)c * CBD;
    float s = 0.0f;
#pragma unroll
    for (int d = 0; d < CBD; ++d) s += row[d] * row[d];
    cbn[c] = s;
}

// ------------------------- weight transpose + split: W [z][K][N] -> T [z][N][K]
__global__ __launch_bounds__(256) void wtrans_kernel(
    const float* __restrict__ W, u16* __restrict__ Th, u16* __restrict__ Tl,
    int K, int N, long inLS, long outLS) {
    __shared__ float t[32][33];
    const float* Ws = W + (size_t)blockIdx.z * inLS;
    u16* Tho = Th + (size_t)blockIdx.z * outLS;
    u16* Tlo = Tl + (size_t)blockIdx.z * outLS;
    int n0 = blockIdx.x * 32, k0 = blockIdx.y * 32;
    int tx = threadIdx.x & 31, ty = threadIdx.x >> 5;
#pragma unroll
    for (int r = ty; r < 32; r += 8) t[r][tx] = Ws[(size_t)(k0 + r) * N + n0 + tx];
    __syncthreads();
#pragma unroll
    for (int r = ty; r < 32; r += 8) {
        float v = t[tx][r];
        size_t o = (size_t)(n0 + r) * K + k0 + tx;
        u16 hh = f2bf(v);
        Tho[o] = hh;
        Tlo[o] = f2bf(v - bf2f(hh));
    }
}

// ---------------- V transpose: head-major qkv slot [16+h][M][64] -> VT [b][d][s]
__global__ __launch_bounds__(256) void vtrans_kernel(
    const u16* __restrict__ Qh, const u16* __restrict__ Ql,
    u16* __restrict__ VTh, u16* __restrict__ VTl) {
    __shared__ u16 t[64][68];
    int s0 = blockIdx.x * 64;       // seq tile
    int hh = blockIdx.y;            // head
    int b = blockIdx.z & 15, plane = blockIdx.z >> 4;
    const u16* src = (plane ? Ql : Qh) + ((size_t)(16 + hh) * MROWS) * 64;
    u16* dst = (plane ? VTl : VTh);
    int tid = threadIdx.x;
    int rr = tid >> 4, c4 = (tid & 15) * 4;
#pragma unroll
    for (int i = 0; i < 4; ++i) {
        int r = rr + i * 16; // seq within tile
        const u16* p = src + (size_t)(b * SEQ + s0 + r) * 64 + c4;
        *(u16x4*)(&t[r][c4]) = *(const u16x4*)p;
    }
    __syncthreads();
#pragma unroll
    for (int i = 0; i < 4; ++i) {
        int r = rr + i * 16; // d-index within head
        u16x4 v;
        v.x = t[c4 + 0][r]; v.y = t[c4 + 1][r]; v.z = t[c4 + 2][r]; v.w = t[c4 + 3][r];
        *(u16x4*)(dst + (size_t)b * SEQ * DMODEL + (size_t)(hh * 64 + r) * SEQ + s0 + c4) = v;
    }
}

// ------------------------------------------------ elementwise fp32 -> (hi,lo)
__global__ void split_kernel(const float* __restrict__ X, u16* __restrict__ H,
                             u16* __restrict__ L, int n) {
    int i = blockIdx.x * 256 + threadIdx.x;
    if (i < n) {
        float v = X[i];
        u16 hh = f2bf(v);
        H[i] = hh;
        L[i] = f2bf(v - bf2f(hh));
    }
}

// ---------------------------------------- layernorm (+split-K reduce folding)
__global__ __launch_bounds__(256) void ln_kernel(
    const float* __restrict__ X,
    const float* __restrict__ C0, const float* __restrict__ C1,
    const float* __restrict__ bias2, const float* __restrict__ pos2,
    float* __restrict__ Xout,
    float* __restrict__ Y, u16* __restrict__ Yh, u16* __restrict__ Yl,
    const float* __restrict__ g, const float* __restrict__ b) {
    int row  = blockIdx.x * 4 + (threadIdx.x >> 6);
    int lane = threadIdx.x & 63;
    float v[8];
    float s = 0.0f;
#pragma unroll
    for (int j = 0; j < 8; ++j) {
        int d = lane + j * 64;
        size_t o = (size_t)row * DMODEL + d;
        float t = X ? X[o] : 0.0f;
        if (C0)    t += C0[o] + C1[o];
        if (bias2) t += bias2[d];
        if (pos2)  t += pos2[(size_t)(row & (SEQ - 1)) * DMODEL + d];
        v[j] = t;
        if (Xout) Xout[o] = t;
        s += t;
    }
#pragma unroll
    for (int off = 32; off; off >>= 1) s += __shfl_xor(s, off);
    float mu  = s * (1.0f / DMODEL);
    float var = 0.0f;
#pragma unroll
    for (int j = 0; j < 8; ++j) { float d = v[j] - mu; var += d * d; }
#pragma unroll
    for (int off = 32; off; off >>= 1) var += __shfl_xor(var, off);
    float r = rsqrtf(var * (1.0f / DMODEL) + 1e-5f);
#pragma unroll
    for (int j = 0; j < 8; ++j) {
        int d = lane + j * 64;
        float y = (v[j] - mu) * r * g[d] + b[d];
        size_t o = (size_t)row * DMODEL + d;
        if (Y) Y[o] = y;
        if (Yh) {
            u16 hh = f2bf(y);
            Yh[o] = hh;
            Yl[o] = f2bf(y - bf2f(hh));
        }
    }
}

// --------------------------------------------------------- bf16x3 MFMA GEMM
// BK=64, XOR-swizzled LDS (conflict-free frag reads), 96 MFMA per barrier-pair.
// kslice>0: split-K partials -> Cs0/Cs1. qkvscatter: store C head-major.
__global__ __launch_bounds__(256) void gemm3_kernel(
    const u16* __restrict__ Ah, const u16* __restrict__ Al,
    const u16* __restrict__ Bh, const u16* __restrict__ Bl,
    float* __restrict__ Cf, u16* __restrict__ Ch, u16* __restrict__ Cl,
    const float* __restrict__ bias, const float* __restrict__ res,
    const float* __restrict__ pos, int M, int N, int K, int gelu,
    float* __restrict__ Cs0, float* __restrict__ Cs1, int kslice, int qkvscatter) {
    __shared__ __align__(16) u16 AsH[128 * 64];
    __shared__ __align__(16) u16 AsL[128 * 64];
    __shared__ __align__(16) u16 BsH[128 * 64];
    __shared__ __align__(16) u16 BsL[128 * 64];

    int tid  = threadIdx.x;
    int w    = tid >> 6, lane = tid & 63;
    int wr   = w >> 1, wc = w & 1;
    int quad = lane >> 4, l16 = lane & 15;
    int m0   = blockIdx.x * 128;
    int n0   = blockIdx.y * 128;
    int ksA  = (kslice > 0) ? blockIdx.z * kslice : 0;
    int ksB  = (kslice > 0) ? ksA + kslice : K;

    f32x4 acc[4][4];
#pragma unroll
    for (int i = 0; i < 4; ++i)
#pragma unroll
        for (int j = 0; j < 4; ++j) acc[i][j] = (f32x4){0.f, 0.f, 0.f, 0.f};

    int ldsoff[4];
    size_t goff[4];
#pragma unroll
    for (int r = 0; r < 4; ++r) {
        int cidx = tid + 256 * r;
        int row = cidx >> 3;
        int cg = (cidx & 7) ^ (row & 7);
        ldsoff[r] = cidx * 8;
        goff[r] = (size_t)row * K + cg * 8;
    }

    const u16* AbaseH = Ah + (size_t)m0 * K;
    const u16* AbaseL = Al + (size_t)m0 * K;
    const u16* BbaseH = Bh + (size_t)n0 * K;
    const u16* BbaseL = Bl + (size_t)n0 * K;

    for (int ks = ksA; ks < ksB; ks += 64) {
        __syncthreads();
#pragma unroll
        for (int r = 0; r < 4; ++r) {
            size_t g = goff[r] + ks;
            async16(&AsH[ldsoff[r]], AbaseH + g);
            async16(&AsL[ldsoff[r]], AbaseL + g);
            async16(&BsH[ldsoff[r]], BbaseH + g);
            async16(&BsL[ldsoff[r]], BbaseL + g);
        }
        __syncthreads();
#pragma unroll
        for (int s = 0; s < 2; ++s) {
            short8 afh[4], afl[4];
#pragma unroll
            for (int i = 0; i < 4; ++i) {
                int row = wr * 64 + i * 16 + l16;
                int off = row * 64 + (((s << 2) | quad) ^ (row & 7)) * 8;
                afh[i] = *(const short8*)&AsH[off];
                afl[i] = *(const short8*)&AsL[off];
            }
#pragma unroll
            for (int j = 0; j < 4; ++j) {
                int rowb = wc * 64 + j * 16 + l16;
                int offb = rowb * 64 + (((s << 2) | quad) ^ (rowb & 7)) * 8;
                short8 bh = *(const short8*)&BsH[offb];
                short8 bl = *(const short8*)&BsL[offb];
#pragma unroll
                for (int i = 0; i < 4; ++i) {
                    acc[i][j] = __builtin_amdgcn_mfma_f32_16x16x32_bf16(afh[i], bh, acc[i][j], 0, 0, 0);
                    acc[i][j] = __builtin_amdgcn_mfma_f32_16x16x32_bf16(afl[i], bh, acc[i][j], 0, 0, 0);
                    acc[i][j] = __builtin_amdgcn_mfma_f32_16x16x32_bf16(afh[i], bl, acc[i][j], 0, 0, 0);
                }
            }
        }
    }

    float* Cspl = (kslice > 0) ? (blockIdx.z ? Cs1 : Cs0) : nullptr;
    int mbase = m0 + wr * 64;
    int nbase = n0 + wc * 64;
#pragma unroll
    for (int mi = 0; mi < 4; ++mi)
#pragma unroll
        for (int ni = 0; ni < 4; ++ni) {
            f32x4 a = acc[mi][ni];
#pragma unroll
            for (int r = 0; r < 4; ++r) {
                int m = mbase + mi * 16 + quad * 4 + r;
                int n = nbase + ni * 16 + l16;
                float v = a[r];
                size_t o = qkvscatter
                    ? ((size_t)(n >> 6) * M + m) * 64 + (n & 63)
                    : (size_t)m * N + n;
                if (Cspl) { Cspl[o] = v; continue; }
                if (bias) v += bias[n];
                if (pos)  v += pos[(size_t)(m & (SEQ - 1)) * N + n];
                if (res)  v += res[(size_t)m * N + n];
                if (gelu) v = gelu_tanh(v);
                if (Cf) Cf[o] = v;
                if (Ch) {
                    u16 hh = f2bf(v);
                    Ch[o] = hh;
                    Cl[o] = f2bf(v - bf2f(hh));
                }
            }
        }
}

// ------------------------------------------------------------ fp32 GEMM (small)
__global__ __launch_bounds__(256) void gemm_kernel(
    const float* __restrict__ A, const float* __restrict__ Bm,
    float* __restrict__ C, const float* __restrict__ bias,
    int M, int N, int K) {
    __shared__ float As[16][68];
    __shared__ float Bs[16][64];
    int tid = threadIdx.x;
    int tx = tid & 15, ty = tid >> 4;
    int a_m = tid >> 2, a_k = (tid & 3) * 4;
    int b_k = tid >> 4, b_n = (tid & 15) * 4;
    const float* Arow = A + (size_t)(blockIdx.x * 64 + a_m) * K;
    const float* Bcol = Bm + (size_t)blockIdx.y * 64 + b_n;
    float acc[4][4] = {};
    for (int k0 = 0; k0 < K; k0 += 16) {
        float4 av = *(const float4*)(Arow + k0 + a_k);
        float4 bv = *(const float4*)(Bcol + (size_t)(k0 + b_k) * N);
        __syncthreads();
        As[a_k + 0][a_m] = av.x; As[a_k + 1][a_m] = av.y;
        As[a_k + 2][a_m] = av.z; As[a_k + 3][a_m] = av.w;
        *(float4*)(&Bs[b_k][b_n]) = bv;
        __syncthreads();
#pragma unroll
        for (int kk = 0; kk < 16; ++kk) {
            float4 a4 = *(const float4*)(&As[kk][ty * 4]);
            float4 b4 = *(const float4*)(&Bs[kk][tx * 4]);
            float ar[4] = {a4.x, a4.y, a4.z, a4.w};
            float br[4] = {b4.x, b4.y, b4.z, b4.w};
#pragma unroll
            for (int i = 0; i < 4; ++i)
#pragma unroll
                for (int j = 0; j < 4; ++j) acc[i][j] = fmaf(ar[i], br[j], acc[i][j]);
        }
    }
    int m0 = blockIdx.x * 64 + ty * 4;
    int n0 = blockIdx.y * 64 + tx * 4;
#pragma unroll
    for (int i = 0; i < 4; ++i) {
        float vv[4];
#pragma unroll
        for (int j = 0; j < 4; ++j) {
            float t = acc[i][j];
            if (bias) t += bias[n0 + j];
            vv[j] = t;
        }
        *(float4*)(C + (size_t)(m0 + i) * N + n0) = make_float4(vv[0], vv[1], vv[2], vv[3]);
    }
}

// ------------------------------------------- flash attention (STATIC-max softmax)
// R10 WINNER (~51us): block-cooperative LDS K/V staging via swizzled async16
// (global load-instrs/block/kt 128 -> 32, full-line coalescing, no VGPR
// round-trip). Static-max softmax. Kept byte-identical.
__global__ __launch_bounds__(256) void attn_flash_kernel(
    const u16* __restrict__ QKh, const u16* __restrict__ QKl,
    const u16* __restrict__ VTh, const u16* __restrict__ VTl,
    u16* __restrict__ Oh, u16* __restrict__ Ol) {
    int bh = blockIdx.x & 127;
    int qt = blockIdx.x >> 7;   // 0..7
    int bb = bh >> 3, hh = bh & 7;

    __shared__ __align__(16) float Pw[4][16 * 68]; // wave-private P tiles (17408 B)
    __shared__ __align__(16) u16 KsH[64 * 64];     // 8KB each
    __shared__ __align__(16) u16 KsL[64 * 64];
    __shared__ __align__(16) u16 VsH[64 * 64];
    __shared__ __align__(16) u16 VsL[64 * 64];

    int tid = threadIdx.x;
    int w = tid >> 6, lane = tid & 63;
    int quad = lane >> 4, l16 = lane & 15;
    int qtile = qt * 4 + w;     // 0..31
    float* P = Pw[w];

    const u16* qrh = QKh + ((size_t)hh * MROWS + bb * SEQ + qtile * 16 + l16) * 64 + quad * 8;
    const u16* qrl = QKl + ((size_t)hh * MROWS + bb * SEQ + qtile * 16 + l16) * 64 + quad * 8;
    short8 Qh0 = *(const short8*)qrh;
    short8 Qh1 = *(const short8*)(qrh + 32);
    short8 Ql0 = *(const short8*)qrl;
    short8 Ql1 = *(const short8*)(qrl + 32);

    float lsum[4] = {0.f, 0.f, 0.f, 0.f};   // per-lane partial row sums
    f32x4 acc[4];
#pragma unroll
    for (int dt = 0; dt < 4; ++dt) acc[dt] = (f32x4){0.f, 0.f, 0.f, 0.f};

    const u16* KbH = QKh + ((size_t)(8 + hh) * MROWS + bb * SEQ) * 64;
    const u16* KbL = QKl + ((size_t)(8 + hh) * MROWS + bb * SEQ) * 64;
    const u16* VbH = VTh + (size_t)bb * SEQ * DMODEL + (size_t)(hh * 64) * SEQ;
    const u16* VbL = VTl + (size_t)bb * SEQ * DMODEL + (size_t)(hh * 64) * SEQ;

    // staging map (gemm3 pattern): 512 chunks/plane, 2 per thread per plane.
    // LDS slot cidx holds global chunk (cidx&7)^(row&7) of row=cidx>>3.
    int ldsoff[2];
    int goffK[2];       // K tile: row stride 64 u16
    size_t goffV[2];    // V tile: row stride SEQ u16
#pragma unroll
    for (int r = 0; r < 2; ++r) {
        int cidx = tid + 256 * r;
        int row = cidx >> 3;
        int cg = (cidx & 7) ^ (row & 7);
        ldsoff[r] = cidx * 8;
        goffK[r] = row * 64 + cg * 8;
        goffV[r] = (size_t)row * SEQ + cg * 8;
    }

    for (int kt = 0; kt < 8; ++kt) {
        int kb = kt * 64;
        __syncthreads();   // previous tile fully consumed by all waves
#pragma unroll
        for (int r = 0; r < 2; ++r) {
            async16(&KsH[ldsoff[r]], KbH + (size_t)kb * 64 + goffK[r]);
            async16(&KsL[ldsoff[r]], KbL + (size_t)kb * 64 + goffK[r]);
            async16(&VsH[ldsoff[r]], VbH + kb + goffV[r]);
            async16(&VsL[ldsoff[r]], VbL + kb + goffV[r]);
        }
        __syncthreads();   // staged (compiler drains vmcnt before barrier)

        // ---- QK^T from LDS -> P = exp(score/8), accumulate row sums ----
#pragma unroll
        for (int s = 0; s < 4; ++s) {
            int row = s * 16 + l16;
            int c0 = (quad ^ (row & 7)) * 8;          // chunk quad
            int c1 = ((quad | 4) ^ (row & 7)) * 8;    // chunk quad+4
            f32x4 a = (f32x4){0.f, 0.f, 0.f, 0.f};
            {
                short8 Kh0 = *(const short8*)&KsH[row * 64 + c0];
                short8 Kh1 = *(const short8*)&KsH[row * 64 + c1];
                a = __builtin_amdgcn_mfma_f32_16x16x32_bf16(Qh0, Kh0, a, 0, 0, 0);
                a = __builtin_amdgcn_mfma_f32_16x16x32_bf16(Qh1, Kh1, a, 0, 0, 0);
                a = __builtin_amdgcn_mfma_f32_16x16x32_bf16(Ql0, Kh0, a, 0, 0, 0);
                a = __builtin_amdgcn_mfma_f32_16x16x32_bf16(Ql1, Kh1, a, 0, 0, 0);
            }
            {
                short8 Kl0 = *(const short8*)&KsL[row * 64 + c0];
                short8 Kl1 = *(const short8*)&KsL[row * 64 + c1];
                a = __builtin_amdgcn_mfma_f32_16x16x32_bf16(Qh0, Kl0, a, 0, 0, 0);
                a = __builtin_amdgcn_mfma_f32_16x16x32_bf16(Qh1, Kl1, a, 0, 0, 0);
            }
#pragma unroll
            for (int r = 0; r < 4; ++r) {
                float p = __expf(a[r] * 0.125f);
                lsum[r] += p;
                P[(quad * 4 + r) * 68 + s * 16 + l16] = p;
            }
        }
        // ---- PV from LDS: ks-outer, ph/pl 8 regs live ----
#pragma unroll
        for (int ks = 0; ks < 2; ++ks) {
            short8 ph, pl;
            {
                const float* src = &P[l16 * 68 + ks * 32 + quad * 8];
                f32x4 a0 = *(const f32x4*)src;
                f32x4 a1 = *(const f32x4*)(src + 4);
                float v[8] = {a0[0], a0[1], a0[2], a0[3], a1[0], a1[1], a1[2], a1[3]};
#pragma unroll
                for (int j = 0; j < 8; ++j) {
                    u16 hv = f2bf(v[j]);
                    ph[j] = (short)hv;
                    pl[j] = (short)f2bf(v[j] - bf2f(hv));
                }
            }
#pragma unroll
            for (int dt = 0; dt < 4; ++dt) {
                int rowv = dt * 16 + l16;
                int cv = (((ks << 2) | quad) ^ (rowv & 7)) * 8;
                short8 Vh = *(const short8*)&VsH[rowv * 64 + cv];
                short8 Vl = *(const short8*)&VsL[rowv * 64 + cv];
                acc[dt] = __builtin_amdgcn_mfma_f32_16x16x32_bf16(ph, Vh, acc[dt], 0, 0, 0);
                acc[dt] = __builtin_amdgcn_mfma_f32_16x16x32_bf16(pl, Vh, acc[dt], 0, 0, 0);
                acc[dt] = __builtin_amdgcn_mfma_f32_16x16x32_bf16(ph, Vl, acc[dt], 0, 0, 0);
            }
        }
    }

    // ---- epilogue: single row-sum reduce (within each quad's 16 lanes) ----
#pragma unroll
    for (int r = 0; r < 4; ++r) {
#pragma unroll
        for (int off = 8; off; off >>= 1) lsum[r] += __shfl_xor(lsum[r], off);
    }
#pragma unroll
    for (int r = 0; r < 4; ++r) {
        float inv = 1.0f / lsum[r];
        size_t rowoff = (size_t)(bb * SEQ + qtile * 16 + quad * 4 + r) * DMODEL + hh * 64;
#pragma unroll
        for (int dt = 0; dt < 4; ++dt) {
            float v = acc[dt][r] * inv;
            u16 hv = f2bf(v);
            Oh[rowoff + dt * 16 + l16] = hv;
            Ol[rowoff + dt * 16 + l16] = f2bf(v - bf2f(hv));
        }
    }
}

// ----------------------------------------------------------------- MFMA VQ
// ROUND 12: ping-pong double-buffered codebook staging. R11's single-buffer
// loop was stage->barrier->compute->barrier serialized: ~1900 cy/iter vs
// ~600cy L2 latency + ~150cy compute. Now: issue async16 for tile t+1 into
// buf[cur^1], compute tile t from buf[cur] (landed at the PREVIOUS barrier),
// then ONE __syncthreads (its implicit vmcnt(0) drain happens after compute
// covered part of the load latency). Writes to buf[cur^1] are safe: all
// waves finished reading it before the previous barrier. Halves barriers,
// converts full-latency stall into max(0, latency - compute). Argmin math
// byte-identical.
__global__ __launch_bounds__(256) void vq3_kernel(
    const float* __restrict__ Z, const u16* __restrict__ Zh, const u16* __restrict__ Zl,
    const u16* __restrict__ CBh, const u16* __restrict__ CBl,
    const float* __restrict__ CB, const float* __restrict__ CBN,
    float* __restrict__ out) {
    __shared__ float sbest[4][16];
    __shared__ int sidx[4][16];
    __shared__ int ibest[16];
    __shared__ float psum[4][64];
    __shared__ float cl4[4];
    __shared__ __align__(16) u16 CsH[2][64 * 64];   // 2 x 8KB ping-pong
    __shared__ __align__(16) u16 CsL[2][64 * 64];   // 2 x 8KB

    int tid = threadIdx.x;
    int w = tid >> 6, lane = tid & 63;
    int quad = lane >> 4, l16 = lane & 15;
    int row0 = blockIdx.x * 16;

    const u16* zph = Zh + (size_t)(row0 + l16) * CBD + quad * 8;
    const u16* zpl = Zl + (size_t)(row0 + l16) * CBD + quad * 8;
    short8 Z0h = *(const short8*)zph;
    short8 Z1h = *(const short8*)(zph + 32);
    short8 Z0l = *(const short8*)zpl;
    short8 Z1l = *(const short8*)(zpl + 32);

    float best[4] = {3.4e38f, 3.4e38f, 3.4e38f, 3.4e38f};
    int bidx[4] = {0, 0, 0, 0};

    // staging map (gemm3/attn pattern): 512 chunks/plane, 2 per thread.
    int ldsoff[2], goffC[2];
#pragma unroll
    for (int r = 0; r < 2; ++r) {
        int cidx = tid + 256 * r;
        int row = cidx >> 3;
        int cg = (cidx & 7) ^ (row & 7);
        ldsoff[r] = cidx * 8;
        goffC[r] = row * 64 + cg * 8;
    }

    int rowc = w * 16 + l16;                     // this wave's code row in tile
    int c0 = (quad ^ (rowc & 7)) * 8;
    int c1 = ((quad | 4) ^ (rowc & 7)) * 8;

    // prologue: stage tile 0 into buf 0
#pragma unroll
    for (int r = 0; r < 2; ++r) {
        async16(&CsH[0][ldsoff[r]], CBh + goffC[r]);
        async16(&CsL[0][ldsoff[r]], CBl + goffC[r]);
    }
    __syncthreads();   // tile 0 landed

    int cur = 0;
    for (int t = 0; t < CBS; t += 64) {
        // issue next tile into the other buffer (loads fly during compute)
        if (t + 64 < CBS) {
#pragma unroll
            for (int r = 0; r < 2; ++r) {
                async16(&CsH[cur ^ 1][ldsoff[r]], CBh + (size_t)(t + 64) * 64 + goffC[r]);
                async16(&CsL[cur ^ 1][ldsoff[r]], CBl + (size_t)(t + 64) * 64 + goffC[r]);
            }
        }

        int code = t + rowc;
        short8 C0h = *(const short8*)&CsH[cur][rowc * 64 + c0];
        short8 C1h = *(const short8*)&CsH[cur][rowc * 64 + c1];
        short8 C0l = *(const short8*)&CsL[cur][rowc * 64 + c0];
        short8 C1l = *(const short8*)&CsL[cur][rowc * 64 + c1];
        float cn = CBN[code];
        f32x4 a = (f32x4){0.f, 0.f, 0.f, 0.f};
        a = __builtin_amdgcn_mfma_f32_16x16x32_bf16(Z0h, C0h, a, 0, 0, 0);
        a = __builtin_amdgcn_mfma_f32_16x16x32_bf16(Z1h, C1h, a, 0, 0, 0);
        a = __builtin_amdgcn_mfma_f32_16x16x32_bf16(Z0l, C0h, a, 0, 0, 0);
        a = __builtin_amdgcn_mfma_f32_16x16x32_bf16(Z1l, C1h, a, 0, 0, 0);
        a = __builtin_amdgcn_mfma_f32_16x16x32_bf16(Z0h, C0l, a, 0, 0, 0);
        a = __builtin_amdgcn_mfma_f32_16x16x32_bf16(Z1h, C1l, a, 0, 0, 0);
#pragma unroll
        for (int r = 0; r < 4; ++r) {
            float s = cn - 2.0f * a[r];
            if (s < best[r]) { best[r] = s; bidx[r] = code; }
        }

        __syncthreads();   // drains next-tile loads; all waves done with cur
        cur ^= 1;
    }

#pragma unroll
    for (int off = 8; off; off >>= 1) {
#pragma unroll
        for (int r = 0; r < 4; ++r) {
            float ov = __shfl_xor(best[r], off);
            int oi = __shfl_xor(bidx[r], off);
            if (ov < best[r] || (ov == best[r] && oi < bidx[r])) { best[r] = ov; bidx[r] = oi; }
        }
    }
    if (l16 == 0) {
#pragma unroll
        for (int r = 0; r < 4; ++r) {
            sbest[w][quad * 4 + r] = best[r];
            sidx[w][quad * 4 + r] = bidx[r];
        }
    }
    __syncthreads();
    if (tid < 16) {
        float bv = sbest[0][tid];
        int bi = sidx[0][tid];
#pragma unroll
        for (int ww = 1; ww < 4; ++ww) {
            float ov = sbest[ww][tid];
            int oi = sidx[ww][tid];
            if (ov < bv || (ov == bv && oi < bi)) { bv = ov; bi = oi; }
        }
        ibest[tid] = bi;
    }
    __syncthreads();

    int d2 = lane;
    float qacc = 0.0f, closs = 0.0f;
#pragma unroll
    for (int j = 0; j < 4; ++j) {
        int r2 = w * 4 + j;
        int bi = ibest[r2];
        float q = CB[(size_t)bi * CBD + d2];
        float z = Z[(size_t)(row0 + r2) * CBD + d2];
        qacc += q;
        float df = q - z;
        closs += df * df;
    }
    psum[w][d2] = qacc;
#pragma unroll
    for (int off = 32; off; off >>= 1) closs += __shfl_xor(closs, off);
    if (d2 == 0) cl4[w] = closs;
    __syncthreads();
    if (tid < 64) {
        float t = psum[0][tid] + psum[1][tid] + psum[2][tid] + psum[3][tid];
        int b = row0 >> 9;
        atomicAdd(out + b * 64 + tid, t);
    }
    if (tid == 0)
        atomicAdd(out + 1024, (cl4[0] + cl4[1] + cl4[2] + cl4[3]) * (1.0f / (float)(MROWS * CBD)));
}

// -------------------------------------------------------------------- launch
extern "C" void kernel_launch(void* const* d_in, const int* in_sizes, int n_in,
                              void* d_out, int out_size, void* d_ws, size_t ws_size,
                              hipStream_t stream) {
    const float* x    = (const float*)d_in[0];
    const float* w_in = (const float*)d_in[1];
    const float* b_in = (const float*)d_in[2];
    const float* pos  = (const float*)d_in[3];
    const float* ln1g = (const float*)d_in[4];
    const float* ln1b = (const float*)d_in[5];
    const float* wq   = (const float*)d_in[6];
    const float* wk   = (const float*)d_in[7];
    const float* wv   = (const float*)d_in[8];
    const float* wo   = (const float*)d_in[9];
    const float* ln2g = (const float*)d_in[10];
    const float* ln2b = (const float*)d_in[11];
    const float* ffw1 = (const float*)d_in[12];
    const float* ffb1 = (const float*)d_in[13];
    const float* ffw2 = (const float*)d_in[14];
    const float* ffb2 = (const float*)d_in[15];
    const float* lnfg = (const float*)d_in[16];
    const float* lnfb = (const float*)d_in[17];
    const float* wout = (const float*)d_in[18];
    const float* bout = (const float*)d_in[19];
    const float* cb   = (const float*)d_in[20];
    float* out = (float*)d_out;

    const size_t MD  = (size_t)MROWS * DMODEL;   // 4,194,304
    const size_t MQ  = (size_t)MROWS * 1536;     // 12,582,912
    const size_t MF  = (size_t)MROWS * DFF;      // 16,777,216

    float* ws   = (float*)d_ws;
    float* h    = ws;
    float* t0   = h + MD;
    float* big  = t0 + MD;                   // MF floats (aliased region)
    float* zb   = big + MF;
    float* cbn  = zb + (size_t)MROWS * CBD;
    u16* cbh    = (u16*)(cbn + CBS);
    u16* cbl    = cbh + (size_t)CBS * CBD;
    u16* t0h    = (u16*)(cbh + 2 * (size_t)CBS * CBD);
    u16* t0l    = t0h + MD;
    u16* wb     = t0l + MD;

    // big aliases
    u16* qkvh = (u16*)big;
    u16* qkvl = qkvh + MQ;
    u16* obh  = qkvl + MQ;
    u16* obl  = obh + MD;
    u16* xh   = obh;
    u16* xl   = obl;
    u16* fmh  = (u16*)big;
    u16* fml  = fmh + MF;
    u16* zbh  = (u16*)big;        // VQ phase: big region is dead
    u16* zbl  = zbh + (size_t)MROWS * CBD;

    const size_t S_WIN  = (size_t)DMODEL * DMODEL;
    const size_t S_QKV  = (size_t)1536 * DMODEL * NDEPTH;
    const size_t S_WO   = S_WIN * NDEPTH;
    const size_t S_FF1  = (size_t)DFF * DMODEL * NDEPTH;
    const size_t S_FF2  = S_FF1;
    u16* winT_h = wb;
    u16* winT_l = winT_h + S_WIN;
    u16* qkvT_h = winT_l + S_WIN;
    u16* qkvT_l = qkvT_h + S_QKV;
    u16* woT_h  = qkvT_l + S_QKV;
    u16* woT_l  = woT_h + S_WO;
    u16* ff1T_h = woT_l + S_WO;
    u16* ff1T_l = ff1T_h + S_FF1;
    u16* ff2T_h = ff1T_l + S_FF1;
    u16* ff2T_l = ff2T_h + S_FF2;
    u16* VTh = ff2T_l + S_FF2;
    u16* VTl = VTh + (size_t)BATCH * SEQ * DMODEL;
    // split-K partial buffers (fp32, M x 512 each)
    float* spK0 = (float*)(VTl + (size_t)BATCH * SEQ * DMODEL);
    float* spK1 = spK0 + MD;

    dim3 blk(256);

    zero_kernel<<<dim3((out_size + 255) / 256), blk, 0, stream>>>(out, out_size);
    cbn_kernel<<<dim3(CBS / 256), blk, 0, stream>>>(cb, cbn);
    split_kernel<<<dim3((int)(CBS * CBD / 256)), blk, 0, stream>>>(cb, cbh, cbl, CBS * CBD);

    wtrans_kernel<<<dim3(16, 16, 1), blk, 0, stream>>>(w_in, winT_h, winT_l, DMODEL, DMODEL, 0, 0);
    wtrans_kernel<<<dim3(16, 16, NDEPTH), blk, 0, stream>>>(
        wq, qkvT_h, qkvT_l, DMODEL, DMODEL, (long)DMODEL * DMODEL, (long)1536 * DMODEL);
    wtrans_kernel<<<dim3(16, 16, NDEPTH), blk, 0, stream>>>(
        wk, qkvT_h + (size_t)512 * DMODEL, qkvT_l + (size_t)512 * DMODEL,
        DMODEL, DMODEL, (long)DMODEL * DMODEL, (long)1536 * DMODEL);
    wtrans_kernel<<<dim3(16, 16, NDEPTH), blk, 0, stream>>>(
        wv, qkvT_h + (size_t)1024 * DMODEL, qkvT_l + (size_t)1024 * DMODEL,
        DMODEL, DMODEL, (long)DMODEL * DMODEL, (long)1536 * DMODEL);
    wtrans_kernel<<<dim3(16, 16, NDEPTH), blk, 0, stream>>>(
        wo, woT_h, woT_l, DMODEL, DMODEL, (long)DMODEL * DMODEL, (long)DMODEL * DMODEL);
    wtrans_kernel<<<dim3(DFF / 32, 16, NDEPTH), blk, 0, stream>>>(
        ffw1, ff1T_h, ff1T_l, DMODEL, DFF, (long)DMODEL * DFF, (long)DFF * DMODEL);
    wtrans_kernel<<<dim3(16, DFF / 32, NDEPTH), blk, 0, stream>>>(
        ffw2, ff2T_h, ff2T_l, DFF, DMODEL, (long)DFF * DMODEL, (long)DMODEL * DFF);

    split_kernel<<<dim3((int)(MD / 256)), blk, 0, stream>>>(x, xh, xl, (int)MD);

    // input projection: split-K=2 -> spK0/spK1 (reduced+pos+bias inside ln1 of layer 0)
    gemm3_kernel<<<dim3(MROWS / 128, DMODEL / 128, 2), blk, 0, stream>>>(
        xh, xl, winT_h, winT_l, nullptr, nullptr, nullptr, nullptr, nullptr, nullptr,
        MROWS, DMODEL, DMODEL, 0, spK0, spK1, 256, 0);

    for (int l = 0; l < NDEPTH; ++l) {
        // ln1 folds: l==0 -> input proj (+b_in+pos); l>0 -> previous ff2 (+ffb2[l-1])
        ln_kernel<<<dim3(MROWS / 4), blk, 0, stream>>>(
            (l == 0) ? nullptr : h, spK0, spK1,
            (l == 0) ? b_in : (ffb2 + (size_t)(l - 1) * DMODEL),
            (l == 0) ? pos : nullptr, h,
            nullptr, t0h, t0l, ln1g + l * DMODEL, ln1b + l * DMODEL);
        // fused QKV -> head-major split planes (slot = part*8+head, each [M][64])
        gemm3_kernel<<<dim3(MROWS / 128, 1536 / 128, 1), blk, 0, stream>>>(
            t0h, t0l, qkvT_h + (size_t)l * 1536 * DMODEL, qkvT_l + (size_t)l * 1536 * DMODEL,
            nullptr, qkvh, qkvl, nullptr, nullptr, nullptr, MROWS, 1536, DMODEL, 0,
            nullptr, nullptr, 0, 1);
        vtrans_kernel<<<dim3(8, 8, 32), blk, 0, stream>>>(qkvh, qkvl, VTh, VTl);
        attn_flash_kernel<<<dim3(1024), blk, 0, stream>>>(
            qkvh, qkvl, VTh, VTl, obh, obl);
        // wo: split-K=2 (reduced + residual inside ln2)
        gemm3_kernel<<<dim3(MROWS / 128, DMODEL / 128, 2), blk, 0, stream>>>(
            obh, obl, woT_h + (size_t)l * S_WIN, woT_l + (size_t)l * S_WIN,
            nullptr, nullptr, nullptr, nullptr, nullptr, nullptr,
            MROWS, DMODEL, DMODEL, 0, spK0, spK1, 256, 0);
        ln_kernel<<<dim3(MROWS / 4), blk, 0, stream>>>(
            h, spK0, spK1, nullptr, nullptr, h,
            nullptr, t0h, t0l, ln2g + l * DMODEL, ln2b + l * DMODEL);
        gemm3_kernel<<<dim3(MROWS / 128, DFF / 128, 1), blk, 0, stream>>>(
            t0h, t0l, ff1T_h + (size_t)l * DFF * DMODEL, ff1T_l + (size_t)l * DFF * DMODEL,
            nullptr, fmh, fml, ffb1 + l * DFF, nullptr, nullptr, MROWS, DFF, DMODEL, 1,
            nullptr, nullptr, 0, 0);
        // ff2: split-K=2 over K=2048 (reduced + ffb2 + residual in next ln1/lnf)
        gemm3_kernel<<<dim3(MROWS / 128, DMODEL / 128, 2), blk, 0, stream>>>(
            fmh, fml, ff2T_h + (size_t)l * DFF * DMODEL, ff2T_l + (size_t)l * DFF * DMODEL,
            nullptr, nullptr, nullptr, nullptr, nullptr, nullptr,
            MROWS, DMODEL, DFF, 0, spK0, spK1, 1024, 0);
    }

    // final ln folds last ff2 (+ffb2[3]); writes fp32 t0 for the out-projection
    ln_kernel<<<dim3(MROWS / 4), blk, 0, stream>>>(
        h, spK0, spK1, ffb2 + (size_t)3 * DMODEL, nullptr, nullptr,
        t0, nullptr, nullptr, lnfg, lnfb);
    gemm_kernel<<<dim3(MROWS / 64, 1), blk, 0, stream>>>(t0, wout, zb, bout, MROWS, CBD, DMODEL);
    split_kernel<<<dim3((int)((size_t)MROWS * CBD / 256)), blk, 0, stream>>>(
        zb, zbh, zbl, MROWS * CBD);
    vq3_kernel<<<dim3(MROWS / 16), blk, 0, stream>>>(zb, zbh, zbl, cbh, cbl, cb, cbn, out);
}